// Round 14
// baseline (248.847 us; speedup 1.0000x reference)
//
#include <hip/hip_runtime.h>
#include <hip/hip_bf16.h>

#define DD 20000
#define DM1 19999
#define NB 128     // batch
#define SCB 625    // scan chunks (= transpose c-tiles)
#define SCH 32     // per-chunk span (625*32 = 20000)
#define KS 128     // GEMM k-split blocks
#define GCH 157    // GEMM k-chunk span (128*157 >= 19999)
#define CMAX 16    // max nnz per Psi column (balanced tree depth <= 15)

typedef __hip_bfloat16 bf16;
typedef __attribute__((ext_vector_type(8))) short short8v;   // 8 bf16 (4 VGPRs)
typedef __attribute__((ext_vector_type(16))) float f32x16;   // MFMA 32x32 acc

// ---------------- device-global scratch (no d_ws dependence) ----------------
// NOTE: never pass these as host-side kernel args (host shadow symbol ->
// garbage device pointer -> aperture fault).
// NOTE2: bulk fp32 atomicAdd to HBM ~775 GB/s RMW-bound; split-K reductions
// use non-atomic partials + a plain-store full reduction.
// NOTE3: same-line atomic cost scales with INSTRUCTION count, not lane count.
// NOTE4 (round-1): fp32 SGEMM tiling is LDS-pipe-bound; bf16 hi/lo-split MFMA
// (3x v_mfma_f32_32x32x16_bf16) fixed it (91->46us).
// NOTE5 (round-3): tree-gather kernels are LOCALITY-bound, not TLP-bound:
// 32 consecutive columns share ~13/16 ancestors; keep 32-col blocks.
// NOTE6 (round-4): k_atb3 46us = partial-RT + mat=2 gather latency.
// NOTE7 (round-5): KS 64 halved grid (Occ 19%); b64 staging at 80B stride =
// 245k bank conflicts. TLP structure > byte savings; 80B-stride LDS is
// conflict-free ONLY for 16B accesses.
// NOTE8 (round-6): k_logits latency chains fixed by 4-col register hoist +
// fusion with BW-bound hx blocks (267->245us).
// NOTE9 (round-9/10): parity interleave useless; VGPR 68 > 64-cliff halves
// waves/SIMD. scanC_S depth 32->8 is the one clear win -- keep it.
// NOTE11 (round-10/11): per-thread serial dtype probe cost 45us in k_trans2.
// x-side vectorized (float4/ushort4) -> 235.8us best.
// NOTE12 (round-12): atb3 software-pipeline NEUTRAL -> reverted.
// NOTE13 (round-13): k_zero fused into k_trans2 (wave-parallel probe:
// 1 load + __all ballot). 226.2us best.
// NOTE14 (round-14): k_aux launch dissolved. scanB's chunk-scan is now
// computed redundantly per scanC block (25M L2-resident loads aggregate,
// ~3us); p0/p1/p2 reduces = 3 extra blocks; CSC scatter + rowgeo move into
// the same launch (depend only on inputs + trans2's zeroed ccnt/cval).
// Launches 8 -> 7; g_part now stays as RAW chunk sums (nobody rewrites it).
__device__ __align__(16) float g_lxT[(size_t)DD * NB];   // log(x+1), (D x B)
__device__ __align__(16) float g_etaT[(size_t)DM1 * NB]; // eta^T (D-1 x B)
__device__ unsigned short g_etaTb[(size_t)DM1 * NB];     // bf16 copy (gathers)
__device__ __align__(16) float g_hxT[(size_t)DM1 * NB];  // hx^T (D-1 x B)
__device__ __align__(16) float g_S[(size_t)(DD + 1) * NB];   // prefix sums of lx
__device__ __align__(16) float g_part[SCB * NB];         // raw chunk sums of lx
__device__ __align__(16) float g_p0[SCB * NB];           // sumx partials
__device__ __align__(16) float g_p1[SCB * NB];           // sum log(x!) partials
__device__ __align__(16) float g_p2[SCB * NB];           // eta^2 partials
__device__ __align__(16) float g_pc[(size_t)KS * 49152]; // GEMM partials (25 MB)
__device__ __align__(16) float g_zT[16384];              // z_mean^T (K x B)
__device__ __align__(16) float g_WtW[16384];
__device__ __align__(16) float g_e0[16384];              // eta @ dec_w (B x K)
__device__ float g_S1[NB], g_S2[NB], g_sumx[NB], g_slg[NB], g_quad1[NB], g_q2[NB];
__device__ float g_tr[4];
__device__ int g_f32flag;                   // 1: float inputs are f32; 0: bf16
__device__ int g_rlo[DM1], g_rmid[DM1], g_rhi[DM1];
__device__ float g_ra[DM1], g_rb[DM1];
__device__ int g_ccnt[DD];                               // per-column nnz
__device__ int g_crow[(size_t)DD * CMAX];                // per-column row ids
__device__ __align__(16) float g_cval[(size_t)DD * CMAX];// per-column values

// log(n!) for n = 0..23
__device__ __constant__ float c_lgf[24] = {
  0.f, 0.f, 0.6931471806f, 1.7917594692f, 3.1780538303f, 4.7874917428f,
  6.5792512120f, 8.5251613611f, 10.6046029027f, 12.8018274801f,
  15.1044125731f, 17.5023078459f, 19.9872144957f, 22.5521638531f,
  25.1912211827f, 27.8992713838f, 30.6718601061f, 33.5050734501f,
  36.3954452081f, 39.3398841872f, 42.3356164608f, 45.3801388985f,
  48.4711813518f, 51.6066755678f};

__device__ __forceinline__ float b2f(bf16 v) { return __bfloat162float(v); }

__device__ __forceinline__ float wave_red_sum(float v) {
#pragma unroll
  for (int off = 32; off > 0; off >>= 1) v += __shfl_down(v, off, 64);
  return v;
}

__device__ __forceinline__ float load_in(const void* src, size_t idx, int f32) {
  return f32 ? ((const float*)src)[idx] : b2f(((const bf16*)src)[idx]);
}

__device__ __forceinline__ int lbound(const int* a, int n, int key) {
  int lo = 0, hi = n;
  while (lo < hi) { int m = (lo + hi) >> 1; if (a[m] < key) lo = m + 1; else hi = m; }
  return lo;
}

// f32 -> bf16 bits, round-to-nearest-even
__device__ __forceinline__ unsigned short f2bf(float f) {
  unsigned u = __float_as_uint(f);
  unsigned r = (u + 0x7fffu + ((u >> 16) & 1u)) >> 16;
  return (unsigned short)r;
}

// ------- fused: zero-init | transpose (B x N) -> fp32 (N x B) + partials ----
// Wave-parallel dtype probe (NOTE13): lane l checks probe value l; __all
// gives every wave the block-uniform answer (1 load + 1 ballot).
// Zero-init (g_cval/ccnt/S1/S2/tr) spread over the linear block ids.
// blocks x<SCB: x path (vectorized, NOTE11). x>=SCB: eta path (NOTE12).
__global__ __launch_bounds__(256)
void k_trans2(const void* __restrict__ xsrc, const void* __restrict__ esrc) {
  int tx = threadIdx.x, ty = threadIdx.y;   // (32, 8)
  int t = ty * 32 + tx;                     // 0..255
  // wave-parallel dtype probe
  float pv = ((const float*)xsrc)[t & 63];
  int f32 = __all(pv >= 0.f && pv < 20.5f && floorf(pv) == pv) ? 1 : 0;
  // fused zero-init (linear block id over (x,y) grid)
  int lb = (int)blockIdx.x * 4 + (int)blockIdx.y;
  int zi = lb * 256 + t;
  if (zi < DD * CMAX) g_cval[zi] = 0.f;     // stale g_crow stays in-bounds
  if (zi < DD) g_ccnt[zi] = 0;
  if (zi < NB) { g_S1[zi] = 0.f; g_S2[zi] = 0.f; }
  if (zi < 4) g_tr[zi] = 0.f;
  if (zi == 0) g_f32flag = f32;             // for later kernels

  if ((int)blockIdx.x < SCB) {
    __shared__ float tileT[32][33];     // [c_local][b_local]
    int bx = blockIdx.x;
    int c0 = bx * 32, b0 = blockIdx.y * 32;
    int row = t >> 3;                   // b_local 0..31
    int coff = (t & 7) * 4;             // c_local base
    float v4[4];
    if (f32) {
      float4 vv = *(const float4*)((const float*)xsrc
                    + (size_t)(b0 + row) * DD + c0 + coff);
      v4[0] = vv.x; v4[1] = vv.y; v4[2] = vv.z; v4[3] = vv.w;
    } else {
      ushort4 uu = *(const ushort4*)((const unsigned short*)xsrc
                    + (size_t)(b0 + row) * DD + c0 + coff);
      v4[0] = __uint_as_float((unsigned)uu.x << 16);
      v4[1] = __uint_as_float((unsigned)uu.y << 16);
      v4[2] = __uint_as_float((unsigned)uu.z << 16);
      v4[3] = __uint_as_float((unsigned)uu.w << 16);
    }
    float r0 = 0.f, r1 = 0.f, r2 = 0.f;
#pragma unroll
    for (int j = 0; j < 4; j++) {
      float v = v4[j];
      float lx = logf(v + 1.0f);
      tileT[coff + j][row] = lx;        // banks: (4k+row) mod 32 -> <=2-way
      r0 += v;
      int ix = (int)(v + 0.5f);
      r1 += (ix < 24) ? c_lgf[ix] : lgammaf(v + 1.0f);
      r2 += lx;
    }
#pragma unroll
    for (int off = 4; off > 0; off >>= 1) {
      r0 += __shfl_down(r0, off, 8);
      r1 += __shfl_down(r1, off, 8);
      r2 += __shfl_down(r2, off, 8);
    }
    if ((t & 7) == 0) {
      size_t o = (size_t)bx * NB + (b0 + row);
      g_p0[o] = r0; g_p1[o] = r1; g_part[o] = r2;
    }
    __syncthreads();
    int cc = t >> 3, boff = (t & 7) * 4;
    float4 w = make_float4(tileT[cc][boff], tileT[cc][boff + 1],
                           tileT[cc][boff + 2], tileT[cc][boff + 3]);
    *(float4*)(g_lxT + (size_t)(c0 + cc) * NB + b0 + boff) = w;
    return;
  }
  // ---- eta path (vectorized, unaligned-safe; NOTE12) ----
  __shared__ float tileT[32][33];
  int bx = (int)blockIdx.x - SCB;
  int c0 = bx * 32, b0 = blockIdx.y * 32;
  int row = t >> 3;                   // b_local 0..31
  int coff = (t & 7) * 4;
  int c = c0 + coff;
  float v4[4];
  if (c + 3 < DM1) {
    if (f32) {
      float tmp[4];
      __builtin_memcpy(tmp, (const float*)esrc + (size_t)(b0 + row) * DM1 + c, 16);
#pragma unroll
      for (int j = 0; j < 4; j++) v4[j] = tmp[j];
    } else {
      unsigned short tmp[4];
      __builtin_memcpy(tmp, (const bf16*)esrc + (size_t)(b0 + row) * DM1 + c, 8);
#pragma unroll
      for (int j = 0; j < 4; j++) v4[j] = __uint_as_float((unsigned)tmp[j] << 16);
    }
  } else {
#pragma unroll
    for (int j = 0; j < 4; j++) {
      int cj = c + j;
      v4[j] = (cj < DM1) ? load_in(esrc, (size_t)(b0 + row) * DM1 + cj, f32) : 0.f;
    }
  }
  float r0 = 0.f;
#pragma unroll
  for (int j = 0; j < 4; j++) {
    float v = v4[j];
    tileT[coff + j][row] = v;
    r0 += v * v;
  }
#pragma unroll
  for (int off = 4; off > 0; off >>= 1) r0 += __shfl_down(r0, off, 8);
  if ((t & 7) == 0) g_p2[(size_t)bx * NB + (b0 + row)] = r0;
  __syncthreads();
  int cc = t >> 3, boff = (t & 7) * 4;
  int cg = c0 + cc;
  if (cg < DM1) {
    float4 w = make_float4(tileT[cc][boff], tileT[cc][boff + 1],
                           tileT[cc][boff + 2], tileT[cc][boff + 3]);
    *(float4*)(g_etaT + (size_t)cg * NB + b0 + boff) = w;
    ushort4 wb;
    wb.x = f2bf(w.x); wb.y = f2bf(w.y); wb.z = f2bf(w.z); wb.w = f2bf(w.w);
    *(ushort4*)(g_etaTb + (size_t)cg * NB + b0 + boff) = wb;
  }
}

// ---- fused scan pass (NOTE14): S-prefix | p-reduces | CSC build | rowgeo ---
// blocks [0,SCB): S prefix for chunk j; the chunk-prefix over g_part[0..j)
//   is computed per-block (4-way strided + LDS combine), replacing scanB.
// blocks [SCB,SCB+3): column reduces of g_p0/g_p1/g_p2 -> sumx/slg/quad1.
// blocks [SCB+3, +nbc): COO->CSC scatter (needs trans2's zeroed ccnt/cval).
// blocks [+nbr): per-row lo/mid/hi/a/b via binary search.
__global__ __launch_bounds__(512)
void k_scan2(const int* __restrict__ rows, const int* __restrict__ cols,
             const void* __restrict__ vals, int nnz, int nbc) {
  int t = threadIdx.x;
  int bxx = blockIdx.x;
  if (bxx < SCB) {
    __shared__ float csum[4][128];
    __shared__ float ksum[4][128];
    int j = bxx;
    int b = t & 127, kg = t >> 7;
    // chunk prefix: sum of g_part[idx][b], idx < j (raw chunk sums)
    float cp = 0.f;
    for (int idx = kg; idx < j; idx += 4)
      cp += g_part[(size_t)idx * NB + b];
    csum[kg][b] = cp;
    // intra-chunk (depth-8 walk, NOTE9)
    int c0 = j * SCH + kg * 8;
    float lv[8];
#pragma unroll
    for (int q = 0; q < 8; q++)
      lv[q] = g_lxT[(size_t)(c0 + q) * NB + b];
    float lsum = 0.f;
#pragma unroll
    for (int q = 0; q < 8; q++) lsum += lv[q];
    ksum[kg][b] = lsum;
    __syncthreads();
    float base = csum[0][b] + csum[1][b] + csum[2][b] + csum[3][b];
    for (int g = 0; g < kg; g++) base += ksum[g][b];
#pragma unroll
    for (int q = 0; q < 8; q++) {
      g_S[(size_t)(c0 + q) * NB + b] = base;
      base += lv[q];
    }
    if (j == SCB - 1 && kg == 3) g_S[(size_t)DD * NB + b] = base;
    return;
  }
  if (bxx < SCB + 3) {
    __shared__ float sr2[4][128];
    int which = bxx - SCB;
    const float* src = (which == 0) ? g_p0 : (which == 1) ? g_p1 : g_p2;
    int b = t & 127, kg = t >> 7;
    float s = 0.f;
    for (int idx = kg; idx < SCB; idx += 4)
      s += src[(size_t)idx * NB + b];
    sr2[kg][b] = s;
    __syncthreads();
    if (kg == 0) {
      float v = sr2[0][b] + sr2[1][b] + sr2[2][b] + sr2[3][b];
      if (which == 0) g_sumx[b] = v;
      else if (which == 1) g_slg[b] = v;
      else g_quad1[b] = v;
    }
    return;
  }
  int f32 = g_f32flag;
  int bz = bxx - SCB - 3;
  if (bz < nbc) {
    int j = bz * 512 + t;
    if (j >= nnz) return;
    int c = cols[j];
    int slot = atomicAdd(&g_ccnt[c], 1);
    if (slot < CMAX) {
      g_crow[(size_t)c * CMAX + slot] = rows[j];
      g_cval[(size_t)c * CMAX + slot] = load_in(vals, j, f32);
    }
    return;
  }
  int r = (bz - nbc) * 512 + t;
  if (r >= DM1) return;
  int s = lbound(rows, nnz, r), e = lbound(rows, nnz, r + 1);
  int lo = cols[s], hi = cols[e - 1] + 1;
  int lo_i = s, hi_i = e - 1;            // vals[s] > 0, vals[e-1] < 0
  while (hi_i - lo_i > 1) {
    int m = (lo_i + hi_i) >> 1;
    if (load_in(vals, m, f32) < 0.f) hi_i = m; else lo_i = m;
  }
  g_rlo[r] = lo; g_rmid[r] = lo + (hi_i - s); g_rhi[r] = hi;
  g_ra[r] = load_in(vals, s, f32);
  g_rb[r] = load_in(vals, e - 1, f32);
}

// ---- fused hx materialization + logits/softmax (round-8 exact) -------------
// blocks [0,SCB): hx[r][b] coalesced from S + row geometry (BW-bound).
// blocks [SCB,2*SCB): logits CSC gather + softmax accum (latency-bound),
// 4-col register load-hoist (NOTE8).
__global__ __launch_bounds__(512)
void k_hxlg() {
  int t = threadIdx.x;
  if ((int)blockIdx.x < SCB) {
    __shared__ int slo[32], smid[32], shi[32];
    __shared__ float sa[32], sb[32];
    int r0 = blockIdx.x * 32;
    if (t < 32) {
      int r = r0 + t;
      if (r < DM1) {
        slo[t] = g_rlo[r]; smid[t] = g_rmid[r]; shi[t] = g_rhi[r];
        sa[t] = g_ra[r];   sb[t] = g_rb[r];
      }
    }
    __syncthreads();
    int b = t & 127, g = t >> 7;      // 4 groups x 8 rows
#pragma unroll
    for (int q = 0; q < 8; q++) {
      int rr = g * 8 + q;
      int r = r0 + rr;
      if (r >= DM1) break;
      float sl = g_S[(size_t)slo[rr]  * NB + b];
      float sm = g_S[(size_t)smid[rr] * NB + b];
      float sh = g_S[(size_t)shi[rr]  * NB + b];
      g_hxT[(size_t)r * NB + b] = sa[rr] * (sm - sl) + sb[rr] * (sh - sm);
    }
    return;
  }
  // ---- logits ----
  __shared__ int   sr[32][CMAX];
  __shared__ float sv[32][CMAX];
  __shared__ float s1s[4][128], s2s[4][128];
  int c0 = ((int)blockIdx.x - SCB) * 32;
  {
    int cc = t >> 4, l = t & 15;   // 512 threads = 32x16 exactly
    sr[cc][l] = g_crow[(size_t)(c0 + cc) * CMAX + l];
    sv[cc][l] = g_cval[(size_t)(c0 + cc) * CMAX + l];
  }
  __syncthreads();
  int b = t & 127;
  int qg = t >> 7;                 // 0..3
  float s1 = 0.f, s2 = 0.f;
#pragma unroll
  for (int q = 0; q < 8; q += 4) {
    int cc = qg * 8 + q;
    unsigned short ev[4][CMAX];    // 64 independent gathers in flight
#pragma unroll
    for (int j = 0; j < 4; j++)
#pragma unroll
      for (int l = 0; l < CMAX; l++)
        ev[j][l] = g_etaTb[(size_t)sr[cc + j][l] * NB + b];
    float lxv[4];
#pragma unroll
    for (int j = 0; j < 4; j++)
      lxv[j] = g_lxT[(size_t)(c0 + cc + j) * NB + b];
#pragma unroll
    for (int j = 0; j < 4; j++) {
      float lg = 0.f;
#pragma unroll
      for (int l = 0; l < CMAX; l++)
        lg += sv[cc + j][l] * __uint_as_float((unsigned)ev[j][l] << 16);
      s1 += expf(lg);
      s2 += (expf(lxv[j]) - 1.0f) * lg;
    }
  }
  s1s[qg][b] = s1;
  s2s[qg][b] = s2;
  __syncthreads();
  if (qg == 0) {
    atomicAdd(&g_S1[b], s1s[0][b] + s1s[1][b] + s1s[2][b] + s1s[3][b]);
    atomicAdd(&g_S2[b], s2s[0][b] + s2s[1][b] + s2s[2][b] + s2s[3][b]);
  }
}

// ---- fused triple GEMM via bf16 hi/lo-split MFMA (round-8/11 exact) --------
// grid (KS, 6): y = mat*2 + jhalf. Block: C tile 128i x 64j, 512 threads =
// 8 waves of one 32x32 MFMA tile each. BK=32 staged per round (b128-only LDS
// at 80B stride -> 0 bank conflicts; NOTE7). Non-pipelined (NOTE12).
// mat 0: A=dec, B=dec -> WtW   mat 1: A=etaT, B=dec -> e0
// mat 2: A=g_hxT (precomputed), B=enc -> z
__global__ __launch_bounds__(512)
void k_atb3(const void* __restrict__ dec, const void* __restrict__ enc) {
  __shared__ unsigned short Ah[128][40], Al[128][40];
  __shared__ unsigned short Bh[64][40],  Bl[64][40];
  int f32 = g_f32flag;
  int mat = blockIdx.y >> 1;
  int j0 = (blockIdx.y & 1) * 64;
  int ks = blockIdx.x * GCH;
  int ke = min(ks + GCH, DM1);
  int t = threadIdx.x;
  int lane = t & 63;
  int w = t >> 6;            // wave 0..7
  int wi = (w >> 1) * 32;    // row tile base
  int wj = (w & 1) * 32;     // col tile base (within 64)
  int ai = t & 127;          // A stage: column i
  int akg = t >> 7;          // A stage: k-group (0..3), 8 k each
  int bj = t & 63;           // B stage: column j (threads 0..255)
  int bkg = (t >> 6) & 3;    // B stage: k-group

  f32x16 acc;
#pragma unroll
  for (int r = 0; r < 16; r++) acc[r] = 0.f;

  for (int kb = ks; kb < ke; kb += 32) {
    float av[8];
#pragma unroll
    for (int q = 0; q < 8; q++) {
      int k = kb + akg * 8 + q;
      float v = 0.f;
      if (k < ke) {
        if (mat == 2)      v = g_hxT[(size_t)k * NB + ai];
        else if (mat == 1) v = g_etaT[(size_t)k * NB + ai];
        else               v = load_in(dec, (size_t)k * 128 + ai, f32);
      }
      av[q] = v;
    }
    float bv[8];
    if (t < 256) {
#pragma unroll
      for (int q = 0; q < 8; q++) {
        int k = kb + bkg * 8 + q;
        float v = 0.f;
        if (k < ke) {
          if (mat == 2) v = load_in(enc, (size_t)(j0 + bj) * DM1 + k, f32);
          else          v = load_in(dec, (size_t)k * 128 + j0 + bj, f32);
        }
        bv[q] = v;
      }
    }
    __syncthreads();   // previous round's fragment reads complete
    {
      short8v h8, l8;
#pragma unroll
      for (int q = 0; q < 8; q++) {
        unsigned short h = f2bf(av[q]);
        float hf = __uint_as_float((unsigned)h << 16);
        h8[q] = (short)h;
        l8[q] = (short)f2bf(av[q] - hf);
      }
      *(short8v*)&Ah[ai][akg * 8] = h8;
      *(short8v*)&Al[ai][akg * 8] = l8;
    }
    if (t < 256) {
      short8v h8, l8;
#pragma unroll
      for (int q = 0; q < 8; q++) {
        unsigned short h = f2bf(bv[q]);
        float hf = __uint_as_float((unsigned)h << 16);
        h8[q] = (short)h;
        l8[q] = (short)f2bf(bv[q] - hf);
      }
      *(short8v*)&Bh[bj][bkg * 8] = h8;
      *(short8v*)&Bl[bj][bkg * 8] = l8;
    }
    __syncthreads();   // tile ready
#pragma unroll
    for (int s = 0; s < 2; s++) {
      int k0 = s * 16 + (lane >> 5) * 8;
      int ar = wi + (lane & 31);
      int bc = wj + (lane & 31);
      short8v a_h = *(const short8v*)&Ah[ar][k0];
      short8v a_l = *(const short8v*)&Al[ar][k0];
      short8v b_h = *(const short8v*)&Bh[bc][k0];
      short8v b_l = *(const short8v*)&Bl[bc][k0];
      acc = __builtin_amdgcn_mfma_f32_32x32x16_bf16(a_h, b_h, acc, 0, 0, 0);
      acc = __builtin_amdgcn_mfma_f32_32x32x16_bf16(a_l, b_h, acc, 0, 0, 0);
      acc = __builtin_amdgcn_mfma_f32_32x32x16_bf16(a_h, b_l, acc, 0, 0, 0);
    }
  }
  // C/D layout: col=lane&31, row=(r&3)+8*(r>>2)+4*(lane>>5)
  float* dst = g_pc + (size_t)blockIdx.x * 49152 + mat * 16384;
  int col = j0 + wj + (lane & 31);
#pragma unroll
  for (int r = 0; r < 16; r++) {
    int row = wi + (r & 3) + 8 * (r >> 2) + 4 * (lane >> 5);
    dst[row * 128 + col] = acc[r];
  }
}

// full reduction of KS partials; PLAIN stores (one writer per element).
// 768 blocks (round-8 exact), 4 threads per element + LDS combine.
__global__ __launch_bounds__(256)
void k_red3() {
  __shared__ float sh[256];
  int t = threadIdx.x;
  int e = blockIdx.x * 64 + (t & 63);
  int sg = t >> 6;               // 0..3
  float acc = 0.f;
#pragma unroll 8
  for (int s = sg * 32; s < sg * 32 + 32; s++)
    acc += g_pc[(size_t)s * 49152 + e];
  sh[t] = acc;
  __syncthreads();
  if (t < 64) {
    float v = sh[t] + sh[t + 64] + sh[t + 128] + sh[t + 192];
    int g = blockIdx.x * 64 + t;
    int m = g >> 14, e2 = g & 16383;
    if (m == 0) g_WtW[e2] = v;
    else if (m == 1) g_e0[e2] = v;
    else g_zT[(e2 & 127) * 128 + (e2 >> 7)] = v;   // zT[h][b]
  }
}

// ---- merged p2t (traces of P) + upost (Neumann quad terms) -----------------
__global__ __launch_bounds__(128)
void k_pu(const void* __restrict__ logvars, const void* __restrict__ lsq) {
  __shared__ float sh0[128], sh1[128], sh2[128], sh3[128], sh4[128], sh5[128];
  __shared__ float sds[128];
  int j = threadIdx.x;
  int f32 = g_f32flag;
  float invvar = expf(-load_in(lsq, 0, f32));
  sds[j] = expf(0.5f * load_in(logvars, j, f32));
  __syncthreads();
  if ((int)blockIdx.x < 128) {
    int i = blockIdx.x;
    float sdj = sds[j];
    float p = sds[i] * sdj * g_WtW[i * 128 + j] * invvar;
    sh0[j] = p;
    __syncthreads();
    float acc = 0.f;
    for (int k = 0; k < 128; k++)
      acc += sh0[k] * (sds[k] * sdj * g_WtW[k * 128 + j] * invvar);
    float v1 = wave_red_sum((i == j) ? p : 0.f);
    float v2 = wave_red_sum(p * p);
    float v3 = wave_red_sum(p * acc);
    float v4 = wave_red_sum(acc * acc);
    if ((j & 63) == 0) {
      atomicAdd(&g_tr[0], v1);
      atomicAdd(&g_tr[1], v2);
      atomicAdd(&g_tr[2], v3);
      atomicAdd(&g_tr[3], v4);
    }
  } else {
    int b = blockIdx.x - 128, k = j;
    float sdk = sds[k];
    sh0[k] = g_zT[(size_t)k * 128 + b];   // z[b, k]
    __syncthreads();
    float e0k = g_e0[b * 128 + k];
    float zWk = 0.f;
    for (int m = 0; m < 128; m++) zWk += sh0[m] * g_WtW[m * 128 + k];
    float u = (e0k - zWk) * sdk;
    sh1[k] = u;
    sh5[k] = sh0[k] * (zWk - 2.f * e0k);
    __syncthreads();
    float v1 = 0.f;
    for (int m = 0; m < 128; m++) v1 += sds[m] * g_WtW[m * 128 + k] * sh1[m];
    v1 *= sdk * invvar;
    sh2[k] = v1;
    __syncthreads();
    float v2 = 0.f;
    for (int m = 0; m < 128; m++) v2 += sds[m] * g_WtW[m * 128 + k] * sh2[m];
    v2 *= sdk * invvar;
    sh3[k] = v2;
    __syncthreads();
    float v3 = 0.f;
    for (int m = 0; m < 128; m++) v3 += sds[m] * g_WtW[m * 128 + k] * sh3[m];
    v3 *= sdk * invvar;
    sh4[k] = u * (u - v1 + v2 - v3);
    __syncthreads();
    for (int s = 64; s > 0; s >>= 1) {
      if (k < s) { sh4[k] += sh4[k + s]; sh5[k] += sh5[k + s]; }
      __syncthreads();
    }
    if (k == 0) {
      g_q2[b] = sh4[0];
      g_quad1[b] += sh5[0];   // quad1 held sum(eta^2) from k_scan2
    }
  }
}

// Output dtype: FLOAT32.
__global__ __launch_bounds__(128)
void k_final(const void* __restrict__ lsq, float* __restrict__ out) {
  __shared__ double red[128];
  __shared__ float redz[128];
  int b = threadIdx.x;
  int f32 = g_f32flag;
  float zs = 0.f;
  for (int i = b; i < 16384; i += 128) { float v = g_zT[i]; zs += v * v; }
  redz[b] = zs;
  const double LOG2PI = 1.837877066409345483560659472811;
  float lsqv = load_in(lsq, 0, f32);
  double var = exp((double)lsqv);
  double lse = log((double)g_S1[b]);
  double sumx = (double)g_sumx[b];
  double t1 = lgamma(sumx + 1.0) - (double)g_slg[b];
  double mult_b = t1 + (double)g_S2[b] - sumx * lse;
  double logdetM = (double)g_tr[0] - 0.5 * (double)g_tr[1]
                 + (1.0 / 3.0) * (double)g_tr[2] - 0.25 * (double)g_tr[3];
  double logdet = (double)DM1 * (double)lsqv + logdetM;
  double quad_b = (double)g_quad1[b] / var - (double)g_q2[b] / (var * var);
  double logit_b = -0.5 * ((double)DM1 * LOG2PI + logdet + quad_b);
  red[b] = mult_b + logit_b;
  __syncthreads();
  for (int s = 64; s > 0; s >>= 1) {
    if (b < s) { red[b] += red[b + s]; redz[b] += redz[b + s]; }
    __syncthreads();
  }
  if (b == 0) {
    double ml = red[0] / 128.0;  // mean_b(mult + logit)
    double prior = -0.5 * (double)redz[0] / 16384.0 - 0.5 * LOG2PI;
    out[0] = (float)(-(ml + prior));
  }
}

extern "C" void kernel_launch(void* const* d_in, const int* in_sizes, int n_in,
                              void* d_out, int out_size, void* d_ws, size_t ws_size,
                              hipStream_t stream) {
  const void* x     = d_in[0];
  const int*  rows  = (const int*)d_in[1];
  const int*  cols  = (const int*)d_in[2];
  const void* vals  = d_in[3];
  const void* enc_w = d_in[4];
  const void* dec_w = d_in[5];
  const void* lvars = d_in[6];
  const void* lsq   = d_in[7];
  const void* eta   = d_in[8];
  float* out = (float*)d_out;
  int nnz = in_sizes[1];
  (void)d_ws; (void)ws_size;

  int nbc = (nnz + 511) / 512;
  int nbr = (DM1 + 511) / 512;

  k_trans2<<<dim3(2 * SCB, 4), dim3(32, 8), 0, stream>>>(x, eta);  // + zero/probe
  k_scan2<<<SCB + 3 + nbc + nbr, 512, 0, stream>>>(rows, cols, vals, nnz, nbc);
  k_hxlg<<<2 * SCB, 512, 0, stream>>>();                // hx | logits fused
  k_atb3<<<dim3(KS, 6), 512, 0, stream>>>(dec_w, enc_w);// WtW|e0|z partials (MFMA)
  k_red3<<<768, 256, 0, stream>>>();
  k_pu<<<256, 128, 0, stream>>>(lvars, lsq);            // traces + quad terms
  k_final<<<1, 128, 0, stream>>>(lsq, out);
}

// Round 15
// 225.383 us; speedup vs baseline: 1.1041x; 1.1041x over previous
//
#include <hip/hip_runtime.h>
#include <hip/hip_bf16.h>

#define DD 20000
#define DM1 19999
#define NB 128     // batch
#define SCB 625    // scan chunks (= transpose c-tiles)
#define SCH 32     // per-chunk span (625*32 = 20000)
#define KS 128     // GEMM k-split blocks
#define GCH 157    // GEMM k-chunk span (128*157 >= 19999)
#define CMAX 16    // max nnz per Psi column (balanced tree depth <= 15)

typedef __hip_bfloat16 bf16;
typedef __attribute__((ext_vector_type(8))) short short8v;   // 8 bf16 (4 VGPRs)
typedef __attribute__((ext_vector_type(16))) float f32x16;   // MFMA 32x32 acc

// ---------------- device-global scratch (no d_ws dependence) ----------------
// NOTE: never pass these as host-side kernel args (host shadow symbol ->
// garbage device pointer -> aperture fault).
// NOTE2: bulk fp32 atomicAdd to HBM ~775 GB/s RMW-bound; split-K reductions
// use non-atomic partials + a plain-store full reduction.
// NOTE3: same-line atomic cost scales with INSTRUCTION count, not lane count.
// NOTE4 (round-1): fp32 SGEMM tiling is LDS-pipe-bound; bf16 hi/lo-split MFMA
// (3x v_mfma_f32_32x32x16_bf16) fixed it (91->46us).
// NOTE5 (round-3): tree-gather kernels are LOCALITY-bound, not TLP-bound:
// 32 consecutive columns share ~13/16 ancestors; keep 32-col blocks.
// NOTE6 (round-4): k_atb3 46us = partial-RT + mat=2 gather latency.
// NOTE7 (round-5): KS 64 halved grid (Occ 19%); b64 staging at 80B stride =
// 245k bank conflicts. TLP structure > byte savings; 80B-stride LDS is
// conflict-free ONLY for 16B accesses.
// NOTE8 (round-6): k_logits latency chains fixed by 4-col register hoist +
// fusion with BW-bound hx blocks (267->245us).
// NOTE9 (round-9/10): parity interleave useless; VGPR 68 > 64-cliff halves
// waves/SIMD. scanC_S depth 32->8 is the one clear win -- keep it.
// NOTE11 (round-10/11): per-thread serial dtype probe cost 45us in k_trans2.
// x-side vectorized (float4/ushort4) -> 235.8us best.
// NOTE12 (round-12): atb3 software-pipeline NEUTRAL -> reverted.
// NOTE13 (round-13): k_zero fused into k_trans2 (wave-parallel probe:
// 1 load + __all ballot). 226.2us best.
// NOTE15 (round-14 post-mortem): dissolving k_aux into the scan launch
// regressed 226->249us. The per-block chunk-prefix (runtime-trip loop up to
// 156 load+add iters) priced at latency*depth, not bytes -- k_scan2 47us,
// Occ 30%, VALU 6.7%. Redundant recompute is only free when its critical
// path is FLAT. Round-15: exact revert to the round-13 configuration.
__device__ __align__(16) float g_lxT[(size_t)DD * NB];   // log(x+1), (D x B)
__device__ __align__(16) float g_etaT[(size_t)DM1 * NB]; // eta^T (D-1 x B)
__device__ unsigned short g_etaTb[(size_t)DM1 * NB];     // bf16 copy (gathers)
__device__ __align__(16) float g_hxT[(size_t)DM1 * NB];  // hx^T (D-1 x B)
__device__ __align__(16) float g_S[(size_t)(DD + 1) * NB];   // prefix sums of lx
__device__ __align__(16) float g_part[SCB * NB];         // scan chunk partials
__device__ __align__(16) float g_p0[SCB * NB];           // sumx partials
__device__ __align__(16) float g_p1[SCB * NB];           // sum log(x!) partials
__device__ __align__(16) float g_p2[SCB * NB];           // eta^2 partials
__device__ __align__(16) float g_pc[(size_t)KS * 49152]; // GEMM partials (25 MB)
__device__ __align__(16) float g_zT[16384];              // z_mean^T (K x B)
__device__ __align__(16) float g_WtW[16384];
__device__ __align__(16) float g_e0[16384];              // eta @ dec_w (B x K)
__device__ float g_S1[NB], g_S2[NB], g_sumx[NB], g_slg[NB], g_quad1[NB], g_q2[NB];
__device__ float g_tr[4];
__device__ int g_f32flag;                   // 1: float inputs are f32; 0: bf16
__device__ int g_rlo[DM1], g_rmid[DM1], g_rhi[DM1];
__device__ float g_ra[DM1], g_rb[DM1];
__device__ int g_ccnt[DD];                               // per-column nnz
__device__ int g_crow[(size_t)DD * CMAX];                // per-column row ids
__device__ __align__(16) float g_cval[(size_t)DD * CMAX];// per-column values

// log(n!) for n = 0..23
__device__ __constant__ float c_lgf[24] = {
  0.f, 0.f, 0.6931471806f, 1.7917594692f, 3.1780538303f, 4.7874917428f,
  6.5792512120f, 8.5251613611f, 10.6046029027f, 12.8018274801f,
  15.1044125731f, 17.5023078459f, 19.9872144957f, 22.5521638531f,
  25.1912211827f, 27.8992713838f, 30.6718601061f, 33.5050734501f,
  36.3954452081f, 39.3398841872f, 42.3356164608f, 45.3801388985f,
  48.4711813518f, 51.6066755678f};

__device__ __forceinline__ float b2f(bf16 v) { return __bfloat162float(v); }

__device__ __forceinline__ float wave_red_sum(float v) {
#pragma unroll
  for (int off = 32; off > 0; off >>= 1) v += __shfl_down(v, off, 64);
  return v;
}

__device__ __forceinline__ float load_in(const void* src, size_t idx, int f32) {
  return f32 ? ((const float*)src)[idx] : b2f(((const bf16*)src)[idx]);
}

__device__ __forceinline__ int lbound(const int* a, int n, int key) {
  int lo = 0, hi = n;
  while (lo < hi) { int m = (lo + hi) >> 1; if (a[m] < key) lo = m + 1; else hi = m; }
  return lo;
}

// f32 -> bf16 bits, round-to-nearest-even
__device__ __forceinline__ unsigned short f2bf(float f) {
  unsigned u = __float_as_uint(f);
  unsigned r = (u + 0x7fffu + ((u >> 16) & 1u)) >> 16;
  return (unsigned short)r;
}

// ------- fused: zero-init | transpose (B x N) -> fp32 (N x B) + partials ----
// Wave-parallel dtype probe (NOTE13): lane l checks probe value l; __all
// gives every wave the block-uniform answer at the cost of 1 load + 1 ballot.
// Zero-init work (g_cval etc.) is spread over the first 1250 linear blocks.
// blocks x<SCB: x path (vectorized, NOTE11). x>=SCB: eta path (NOTE12).
__global__ __launch_bounds__(256)
void k_trans2(const void* __restrict__ xsrc, const void* __restrict__ esrc) {
  int tx = threadIdx.x, ty = threadIdx.y;   // (32, 8)
  int t = ty * 32 + tx;                     // 0..255
  // wave-parallel dtype probe
  float pv = ((const float*)xsrc)[t & 63];
  int f32 = __all(pv >= 0.f && pv < 20.5f && floorf(pv) == pv) ? 1 : 0;
  // fused zero-init (linear block id over (x,y) grid)
  int lb = (int)blockIdx.x * 4 + (int)blockIdx.y;
  int zi = lb * 256 + t;
  if (zi < DD * CMAX) g_cval[zi] = 0.f;     // stale g_crow stays in-bounds
  if (zi < DD) g_ccnt[zi] = 0;
  if (zi < NB) { g_S1[zi] = 0.f; g_S2[zi] = 0.f; }
  if (zi < 4) g_tr[zi] = 0.f;
  if (zi == 0) g_f32flag = f32;             // for later kernels

  if ((int)blockIdx.x < SCB) {
    __shared__ float tileT[32][33];     // [c_local][b_local]
    int bx = blockIdx.x;
    int c0 = bx * 32, b0 = blockIdx.y * 32;
    int row = t >> 3;                   // b_local 0..31
    int coff = (t & 7) * 4;             // c_local base
    float v4[4];
    if (f32) {
      float4 vv = *(const float4*)((const float*)xsrc
                    + (size_t)(b0 + row) * DD + c0 + coff);
      v4[0] = vv.x; v4[1] = vv.y; v4[2] = vv.z; v4[3] = vv.w;
    } else {
      ushort4 uu = *(const ushort4*)((const unsigned short*)xsrc
                    + (size_t)(b0 + row) * DD + c0 + coff);
      v4[0] = __uint_as_float((unsigned)uu.x << 16);
      v4[1] = __uint_as_float((unsigned)uu.y << 16);
      v4[2] = __uint_as_float((unsigned)uu.z << 16);
      v4[3] = __uint_as_float((unsigned)uu.w << 16);
    }
    float r0 = 0.f, r1 = 0.f, r2 = 0.f;
#pragma unroll
    for (int j = 0; j < 4; j++) {
      float v = v4[j];
      float lx = logf(v + 1.0f);
      tileT[coff + j][row] = lx;        // banks: (4k+row) mod 32 -> <=2-way
      r0 += v;
      int ix = (int)(v + 0.5f);
      r1 += (ix < 24) ? c_lgf[ix] : lgammaf(v + 1.0f);
      r2 += lx;
    }
#pragma unroll
    for (int off = 4; off > 0; off >>= 1) {
      r0 += __shfl_down(r0, off, 8);
      r1 += __shfl_down(r1, off, 8);
      r2 += __shfl_down(r2, off, 8);
    }
    if ((t & 7) == 0) {
      size_t o = (size_t)bx * NB + (b0 + row);
      g_p0[o] = r0; g_p1[o] = r1; g_part[o] = r2;
    }
    __syncthreads();
    int cc = t >> 3, boff = (t & 7) * 4;
    float4 w = make_float4(tileT[cc][boff], tileT[cc][boff + 1],
                           tileT[cc][boff + 2], tileT[cc][boff + 3]);
    *(float4*)(g_lxT + (size_t)(c0 + cc) * NB + b0 + boff) = w;
    return;
  }
  // ---- eta path (vectorized, unaligned-safe; NOTE12) ----
  __shared__ float tileT[32][33];
  int bx = (int)blockIdx.x - SCB;
  int c0 = bx * 32, b0 = blockIdx.y * 32;
  int row = t >> 3;                   // b_local 0..31
  int coff = (t & 7) * 4;
  int c = c0 + coff;
  float v4[4];
  if (c + 3 < DM1) {
    if (f32) {
      float tmp[4];
      __builtin_memcpy(tmp, (const float*)esrc + (size_t)(b0 + row) * DM1 + c, 16);
#pragma unroll
      for (int j = 0; j < 4; j++) v4[j] = tmp[j];
    } else {
      unsigned short tmp[4];
      __builtin_memcpy(tmp, (const bf16*)esrc + (size_t)(b0 + row) * DM1 + c, 8);
#pragma unroll
      for (int j = 0; j < 4; j++) v4[j] = __uint_as_float((unsigned)tmp[j] << 16);
    }
  } else {
#pragma unroll
    for (int j = 0; j < 4; j++) {
      int cj = c + j;
      v4[j] = (cj < DM1) ? load_in(esrc, (size_t)(b0 + row) * DM1 + cj, f32) : 0.f;
    }
  }
  float r0 = 0.f;
#pragma unroll
  for (int j = 0; j < 4; j++) {
    float v = v4[j];
    tileT[coff + j][row] = v;
    r0 += v * v;
  }
#pragma unroll
  for (int off = 4; off > 0; off >>= 1) r0 += __shfl_down(r0, off, 8);
  if ((t & 7) == 0) g_p2[(size_t)bx * NB + (b0 + row)] = r0;
  __syncthreads();
  int cc = t >> 3, boff = (t & 7) * 4;
  int cg = c0 + cc;
  if (cg < DM1) {
    float4 w = make_float4(tileT[cc][boff], tileT[cc][boff + 1],
                           tileT[cc][boff + 2], tileT[cc][boff + 3]);
    *(float4*)(g_etaT + (size_t)cg * NB + b0 + boff) = w;
    ushort4 wb;
    wb.x = f2bf(w.x); wb.y = f2bf(w.y); wb.z = f2bf(w.z); wb.w = f2bf(w.w);
    *(ushort4*)(g_etaTb + (size_t)cg * NB + b0 + boff) = wb;
  }
}

// ---- fused aux pass: CSC build | row geometry | scanB (all post-trans2) ----
__global__ __launch_bounds__(256)
void k_aux(const int* __restrict__ rows, const int* __restrict__ cols,
           const void* __restrict__ vals, int nnz, int nbc, int nbr) {
  int f32 = g_f32flag;
  int bxx = blockIdx.x;
  if (bxx < nbc) {
    int j = bxx * 256 + threadIdx.x;
    if (j >= nnz) return;
    int c = cols[j];
    int slot = atomicAdd(&g_ccnt[c], 1);
    if (slot < CMAX) {
      g_crow[(size_t)c * CMAX + slot] = rows[j];
      g_cval[(size_t)c * CMAX + slot] = load_in(vals, j, f32);
    }
    return;
  }
  if (bxx < nbc + nbr) {
    int r = (bxx - nbc) * 256 + threadIdx.x;
    if (r >= DM1) return;
    int s = lbound(rows, nnz, r), e = lbound(rows, nnz, r + 1);
    int lo = cols[s], hi = cols[e - 1] + 1;
    int lo_i = s, hi_i = e - 1;            // vals[s] > 0, vals[e-1] < 0
    while (hi_i - lo_i > 1) {
      int m = (lo_i + hi_i) >> 1;
      if (load_in(vals, m, f32) < 0.f) hi_i = m; else lo_i = m;
    }
    g_rlo[r] = lo; g_rmid[r] = lo + (hi_i - s); g_rhi[r] = hi;
    g_ra[r] = load_in(vals, s, f32);
    g_rb[r] = load_in(vals, e - 1, f32);
    return;
  }
  // ---- scanB ----
  __shared__ float sc[256];
  int b = bxx - nbc - nbr;      // 0..127
  int t = threadIdx.x;          // chunks 3t..3t+2
  float v[3];
  float s = 0.f;
#pragma unroll
  for (int q = 0; q < 3; q++) {
    int idx = t * 3 + q;
    v[q] = (idx < SCB) ? g_part[(size_t)idx * NB + b] : 0.f;
    s += v[q];
  }
  sc[t] = s;
  __syncthreads();
  for (int d = 1; d < 256; d <<= 1) {
    float add = (t >= d) ? sc[t - d] : 0.f;
    __syncthreads();
    sc[t] += add;
    __syncthreads();
  }
  float run = (t == 0) ? 0.f : sc[t - 1];
#pragma unroll
  for (int q = 0; q < 3; q++) {
    int idx = t * 3 + q;
    if (idx < SCB) {
      float tmp = v[q];
      g_part[(size_t)idx * NB + b] = run;
      run += tmp;
    }
  }
  float s0 = 0.f, s1 = 0.f, s2 = 0.f;
  for (int idx = t; idx < SCB; idx += 256) {
    size_t o = (size_t)idx * NB + b;
    s0 += g_p0[o];
    s1 += g_p1[o];
    s2 += g_p2[o];
  }
  __syncthreads();
  sc[t] = s0;
  __syncthreads();
  for (int d = 128; d > 0; d >>= 1) { if (t < d) sc[t] += sc[t + d]; __syncthreads(); }
  if (t == 0) g_sumx[b] = sc[0];
  __syncthreads();
  sc[t] = s1;
  __syncthreads();
  for (int d = 128; d > 0; d >>= 1) { if (t < d) sc[t] += sc[t + d]; __syncthreads(); }
  if (t == 0) g_slg[b] = sc[0];
  __syncthreads();
  sc[t] = s2;
  __syncthreads();
  for (int d = 128; d > 0; d >>= 1) { if (t < d) sc[t] += sc[t + d]; __syncthreads(); }
  if (t == 0) g_quad1[b] = sc[0];
}

// exclusive prefix S[c] of lx; serial depth 8 (NOTE9). 512 threads:
// (kg 0..3) x (b 0..127); each thread loads its 8 lx up-front, LDS combine
// gives the per-(kg,b) base, then an 8-step register walk writes S.
__global__ __launch_bounds__(512)
void k_scanC_S() {
  __shared__ float ksum[4][128];
  int j = blockIdx.x;
  int t = threadIdx.x;
  int b = t & 127, kg = t >> 7;
  int c0 = j * SCH + kg * 8;          // SCH==32 divides DD exactly
  float lv[8];
#pragma unroll
  for (int q = 0; q < 8; q++)
    lv[q] = g_lxT[(size_t)(c0 + q) * NB + b];
  float lsum = 0.f;
#pragma unroll
  for (int q = 0; q < 8; q++) lsum += lv[q];
  ksum[kg][b] = lsum;
  __syncthreads();
  float base = g_part[(size_t)j * NB + b];
  for (int g = 0; g < kg; g++) base += ksum[g][b];
#pragma unroll
  for (int q = 0; q < 8; q++) {
    g_S[(size_t)(c0 + q) * NB + b] = base;
    base += lv[q];
  }
  if (j == SCB - 1 && kg == 3) g_S[(size_t)DD * NB + b] = base;
}

// ---- fused hx materialization + logits/softmax (round-8 exact) -------------
// blocks [0,SCB): hx[r][b] coalesced from S + row geometry (BW-bound).
// blocks [SCB,2*SCB): logits CSC gather + softmax accum (latency-bound),
// 4-col register load-hoist (NOTE8).
__global__ __launch_bounds__(512)
void k_hxlg() {
  int t = threadIdx.x;
  if ((int)blockIdx.x < SCB) {
    __shared__ int slo[32], smid[32], shi[32];
    __shared__ float sa[32], sb[32];
    int r0 = blockIdx.x * 32;
    if (t < 32) {
      int r = r0 + t;
      if (r < DM1) {
        slo[t] = g_rlo[r]; smid[t] = g_rmid[r]; shi[t] = g_rhi[r];
        sa[t] = g_ra[r];   sb[t] = g_rb[r];
      }
    }
    __syncthreads();
    int b = t & 127, g = t >> 7;      // 4 groups x 8 rows
#pragma unroll
    for (int q = 0; q < 8; q++) {
      int rr = g * 8 + q;
      int r = r0 + rr;
      if (r >= DM1) break;
      float sl = g_S[(size_t)slo[rr]  * NB + b];
      float sm = g_S[(size_t)smid[rr] * NB + b];
      float sh = g_S[(size_t)shi[rr]  * NB + b];
      g_hxT[(size_t)r * NB + b] = sa[rr] * (sm - sl) + sb[rr] * (sh - sm);
    }
    return;
  }
  // ---- logits ----
  __shared__ int   sr[32][CMAX];
  __shared__ float sv[32][CMAX];
  __shared__ float s1s[4][128], s2s[4][128];
  int c0 = ((int)blockIdx.x - SCB) * 32;
  {
    int cc = t >> 4, l = t & 15;   // 512 threads = 32x16 exactly
    sr[cc][l] = g_crow[(size_t)(c0 + cc) * CMAX + l];
    sv[cc][l] = g_cval[(size_t)(c0 + cc) * CMAX + l];
  }
  __syncthreads();
  int b = t & 127;
  int qg = t >> 7;                 // 0..3
  float s1 = 0.f, s2 = 0.f;
#pragma unroll
  for (int q = 0; q < 8; q += 4) {
    int cc = qg * 8 + q;
    unsigned short ev[4][CMAX];    // 64 independent gathers in flight
#pragma unroll
    for (int j = 0; j < 4; j++)
#pragma unroll
      for (int l = 0; l < CMAX; l++)
        ev[j][l] = g_etaTb[(size_t)sr[cc + j][l] * NB + b];
    float lxv[4];
#pragma unroll
    for (int j = 0; j < 4; j++)
      lxv[j] = g_lxT[(size_t)(c0 + cc + j) * NB + b];
#pragma unroll
    for (int j = 0; j < 4; j++) {
      float lg = 0.f;
#pragma unroll
      for (int l = 0; l < CMAX; l++)
        lg += sv[cc + j][l] * __uint_as_float((unsigned)ev[j][l] << 16);
      s1 += expf(lg);
      s2 += (expf(lxv[j]) - 1.0f) * lg;
    }
  }
  s1s[qg][b] = s1;
  s2s[qg][b] = s2;
  __syncthreads();
  if (qg == 0) {
    atomicAdd(&g_S1[b], s1s[0][b] + s1s[1][b] + s1s[2][b] + s1s[3][b]);
    atomicAdd(&g_S2[b], s2s[0][b] + s2s[1][b] + s2s[2][b] + s2s[3][b]);
  }
}

// ---- fused triple GEMM via bf16 hi/lo-split MFMA (round-8/11 exact) --------
// grid (KS, 6): y = mat*2 + jhalf. Block: C tile 128i x 64j, 512 threads =
// 8 waves of one 32x32 MFMA tile each. BK=32 staged per round (b128-only LDS
// at 80B stride -> 0 bank conflicts; NOTE7). Non-pipelined (NOTE12).
// mat 0: A=dec, B=dec -> WtW   mat 1: A=etaT, B=dec -> e0
// mat 2: A=g_hxT (precomputed), B=enc -> z
__global__ __launch_bounds__(512)
void k_atb3(const void* __restrict__ dec, const void* __restrict__ enc) {
  __shared__ unsigned short Ah[128][40], Al[128][40];
  __shared__ unsigned short Bh[64][40],  Bl[64][40];
  int f32 = g_f32flag;
  int mat = blockIdx.y >> 1;
  int j0 = (blockIdx.y & 1) * 64;
  int ks = blockIdx.x * GCH;
  int ke = min(ks + GCH, DM1);
  int t = threadIdx.x;
  int lane = t & 63;
  int w = t >> 6;            // wave 0..7
  int wi = (w >> 1) * 32;    // row tile base
  int wj = (w & 1) * 32;     // col tile base (within 64)
  int ai = t & 127;          // A stage: column i
  int akg = t >> 7;          // A stage: k-group (0..3), 8 k each
  int bj = t & 63;           // B stage: column j (threads 0..255)
  int bkg = (t >> 6) & 3;    // B stage: k-group

  f32x16 acc;
#pragma unroll
  for (int r = 0; r < 16; r++) acc[r] = 0.f;

  for (int kb = ks; kb < ke; kb += 32) {
    float av[8];
#pragma unroll
    for (int q = 0; q < 8; q++) {
      int k = kb + akg * 8 + q;
      float v = 0.f;
      if (k < ke) {
        if (mat == 2)      v = g_hxT[(size_t)k * NB + ai];
        else if (mat == 1) v = g_etaT[(size_t)k * NB + ai];
        else               v = load_in(dec, (size_t)k * 128 + ai, f32);
      }
      av[q] = v;
    }
    float bv[8];
    if (t < 256) {
#pragma unroll
      for (int q = 0; q < 8; q++) {
        int k = kb + bkg * 8 + q;
        float v = 0.f;
        if (k < ke) {
          if (mat == 2) v = load_in(enc, (size_t)(j0 + bj) * DM1 + k, f32);
          else          v = load_in(dec, (size_t)k * 128 + j0 + bj, f32);
        }
        bv[q] = v;
      }
    }
    __syncthreads();   // previous round's fragment reads complete
    {
      short8v h8, l8;
#pragma unroll
      for (int q = 0; q < 8; q++) {
        unsigned short h = f2bf(av[q]);
        float hf = __uint_as_float((unsigned)h << 16);
        h8[q] = (short)h;
        l8[q] = (short)f2bf(av[q] - hf);
      }
      *(short8v*)&Ah[ai][akg * 8] = h8;
      *(short8v*)&Al[ai][akg * 8] = l8;
    }
    if (t < 256) {
      short8v h8, l8;
#pragma unroll
      for (int q = 0; q < 8; q++) {
        unsigned short h = f2bf(bv[q]);
        float hf = __uint_as_float((unsigned)h << 16);
        h8[q] = (short)h;
        l8[q] = (short)f2bf(bv[q] - hf);
      }
      *(short8v*)&Bh[bj][bkg * 8] = h8;
      *(short8v*)&Bl[bj][bkg * 8] = l8;
    }
    __syncthreads();   // tile ready
#pragma unroll
    for (int s = 0; s < 2; s++) {
      int k0 = s * 16 + (lane >> 5) * 8;
      int ar = wi + (lane & 31);
      int bc = wj + (lane & 31);
      short8v a_h = *(const short8v*)&Ah[ar][k0];
      short8v a_l = *(const short8v*)&Al[ar][k0];
      short8v b_h = *(const short8v*)&Bh[bc][k0];
      short8v b_l = *(const short8v*)&Bl[bc][k0];
      acc = __builtin_amdgcn_mfma_f32_32x32x16_bf16(a_h, b_h, acc, 0, 0, 0);
      acc = __builtin_amdgcn_mfma_f32_32x32x16_bf16(a_l, b_h, acc, 0, 0, 0);
      acc = __builtin_amdgcn_mfma_f32_32x32x16_bf16(a_h, b_l, acc, 0, 0, 0);
    }
  }
  // C/D layout: col=lane&31, row=(r&3)+8*(r>>2)+4*(lane>>5)
  float* dst = g_pc + (size_t)blockIdx.x * 49152 + mat * 16384;
  int col = j0 + wj + (lane & 31);
#pragma unroll
  for (int r = 0; r < 16; r++) {
    int row = wi + (r & 3) + 8 * (r >> 2) + 4 * (lane >> 5);
    dst[row * 128 + col] = acc[r];
  }
}

// full reduction of KS partials; PLAIN stores (one writer per element).
// 768 blocks (round-8 exact), 4 threads per element + LDS combine.
__global__ __launch_bounds__(256)
void k_red3() {
  __shared__ float sh[256];
  int t = threadIdx.x;
  int e = blockIdx.x * 64 + (t & 63);
  int sg = t >> 6;               // 0..3
  float acc = 0.f;
#pragma unroll 8
  for (int s = sg * 32; s < sg * 32 + 32; s++)
    acc += g_pc[(size_t)s * 49152 + e];
  sh[t] = acc;
  __syncthreads();
  if (t < 64) {
    float v = sh[t] + sh[t + 64] + sh[t + 128] + sh[t + 192];
    int g = blockIdx.x * 64 + t;
    int m = g >> 14, e2 = g & 16383;
    if (m == 0) g_WtW[e2] = v;
    else if (m == 1) g_e0[e2] = v;
    else g_zT[(e2 & 127) * 128 + (e2 >> 7)] = v;   // zT[h][b]
  }
}

// ---- merged p2t (traces of P) + upost (Neumann quad terms) -----------------
__global__ __launch_bounds__(128)
void k_pu(const void* __restrict__ logvars, const void* __restrict__ lsq) {
  __shared__ float sh0[128], sh1[128], sh2[128], sh3[128], sh4[128], sh5[128];
  __shared__ float sds[128];
  int j = threadIdx.x;
  int f32 = g_f32flag;
  float invvar = expf(-load_in(lsq, 0, f32));
  sds[j] = expf(0.5f * load_in(logvars, j, f32));
  __syncthreads();
  if ((int)blockIdx.x < 128) {
    int i = blockIdx.x;
    float sdj = sds[j];
    float p = sds[i] * sdj * g_WtW[i * 128 + j] * invvar;
    sh0[j] = p;
    __syncthreads();
    float acc = 0.f;
    for (int k = 0; k < 128; k++)
      acc += sh0[k] * (sds[k] * sdj * g_WtW[k * 128 + j] * invvar);
    float v1 = wave_red_sum((i == j) ? p : 0.f);
    float v2 = wave_red_sum(p * p);
    float v3 = wave_red_sum(p * acc);
    float v4 = wave_red_sum(acc * acc);
    if ((j & 63) == 0) {
      atomicAdd(&g_tr[0], v1);
      atomicAdd(&g_tr[1], v2);
      atomicAdd(&g_tr[2], v3);
      atomicAdd(&g_tr[3], v4);
    }
  } else {
    int b = blockIdx.x - 128, k = j;
    float sdk = sds[k];
    sh0[k] = g_zT[(size_t)k * 128 + b];   // z[b, k]
    __syncthreads();
    float e0k = g_e0[b * 128 + k];
    float zWk = 0.f;
    for (int m = 0; m < 128; m++) zWk += sh0[m] * g_WtW[m * 128 + k];
    float u = (e0k - zWk) * sdk;
    sh1[k] = u;
    sh5[k] = sh0[k] * (zWk - 2.f * e0k);
    __syncthreads();
    float v1 = 0.f;
    for (int m = 0; m < 128; m++) v1 += sds[m] * g_WtW[m * 128 + k] * sh1[m];
    v1 *= sdk * invvar;
    sh2[k] = v1;
    __syncthreads();
    float v2 = 0.f;
    for (int m = 0; m < 128; m++) v2 += sds[m] * g_WtW[m * 128 + k] * sh2[m];
    v2 *= sdk * invvar;
    sh3[k] = v2;
    __syncthreads();
    float v3 = 0.f;
    for (int m = 0; m < 128; m++) v3 += sds[m] * g_WtW[m * 128 + k] * sh3[m];
    v3 *= sdk * invvar;
    sh4[k] = u * (u - v1 + v2 - v3);
    __syncthreads();
    for (int s = 64; s > 0; s >>= 1) {
      if (k < s) { sh4[k] += sh4[k + s]; sh5[k] += sh5[k + s]; }
      __syncthreads();
    }
    if (k == 0) {
      g_q2[b] = sh4[0];
      g_quad1[b] += sh5[0];   // quad1 held sum(eta^2) from scanB
    }
  }
}

// Output dtype: FLOAT32.
__global__ __launch_bounds__(128)
void k_final(const void* __restrict__ lsq, float* __restrict__ out) {
  __shared__ double red[128];
  __shared__ float redz[128];
  int b = threadIdx.x;
  int f32 = g_f32flag;
  float zs = 0.f;
  for (int i = b; i < 16384; i += 128) { float v = g_zT[i]; zs += v * v; }
  redz[b] = zs;
  const double LOG2PI = 1.837877066409345483560659472811;
  float lsqv = load_in(lsq, 0, f32);
  double var = exp((double)lsqv);
  double lse = log((double)g_S1[b]);
  double sumx = (double)g_sumx[b];
  double t1 = lgamma(sumx + 1.0) - (double)g_slg[b];
  double mult_b = t1 + (double)g_S2[b] - sumx * lse;
  double logdetM = (double)g_tr[0] - 0.5 * (double)g_tr[1]
                 + (1.0 / 3.0) * (double)g_tr[2] - 0.25 * (double)g_tr[3];
  double logdet = (double)DM1 * (double)lsqv + logdetM;
  double quad_b = (double)g_quad1[b] / var - (double)g_q2[b] / (var * var);
  double logit_b = -0.5 * ((double)DM1 * LOG2PI + logdet + quad_b);
  red[b] = mult_b + logit_b;
  __syncthreads();
  for (int s = 64; s > 0; s >>= 1) {
    if (b < s) { red[b] += red[b + s]; redz[b] += redz[b + s]; }
    __syncthreads();
  }
  if (b == 0) {
    double ml = red[0] / 128.0;  // mean_b(mult + logit)
    double prior = -0.5 * (double)redz[0] / 16384.0 - 0.5 * LOG2PI;
    out[0] = (float)(-(ml + prior));
  }
}

extern "C" void kernel_launch(void* const* d_in, const int* in_sizes, int n_in,
                              void* d_out, int out_size, void* d_ws, size_t ws_size,
                              hipStream_t stream) {
  const void* x     = d_in[0];
  const int*  rows  = (const int*)d_in[1];
  const int*  cols  = (const int*)d_in[2];
  const void* vals  = d_in[3];
  const void* enc_w = d_in[4];
  const void* dec_w = d_in[5];
  const void* lvars = d_in[6];
  const void* lsq   = d_in[7];
  const void* eta   = d_in[8];
  float* out = (float*)d_out;
  int nnz = in_sizes[1];
  (void)d_ws; (void)ws_size;

  int nbc = (nnz + 255) / 256;
  int nbr = (DM1 + 255) / 256;

  k_trans2<<<dim3(2 * SCB, 4), dim3(32, 8), 0, stream>>>(x, eta);  // + zero/probe
  k_aux<<<nbc + nbr + 128, 256, 0, stream>>>(rows, cols, vals, nnz, nbc, nbr);
  k_scanC_S<<<SCB, 512, 0, stream>>>();                 // S prefix (depth 8)
  k_hxlg<<<2 * SCB, 512, 0, stream>>>();                // hx | logits fused
  k_atb3<<<dim3(KS, 6), 512, 0, stream>>>(dec_w, enc_w);// WtW|e0|z partials (MFMA)
  k_red3<<<768, 256, 0, stream>>>();
  k_pu<<<256, 128, 0, stream>>>(lvars, lsq);            // traces + quad terms
  k_final<<<1, 128, 0, stream>>>(lsq, out);
}

// Round 16
// 223.467 us; speedup vs baseline: 1.1136x; 1.0086x over previous
//
#include <hip/hip_runtime.h>
#include <hip/hip_bf16.h>

#define DD 20000
#define DM1 19999
#define NB 128     // batch
#define SCB 625    // scan chunks (= transpose c-tiles)
#define SCH 32     // per-chunk span (625*32 = 20000)
#define KS 128     // GEMM k-split blocks
#define GCH 157    // GEMM k-chunk span (128*157 >= 19999)
#define CMAX 16    // max nnz per Psi column (balanced tree depth <= 15)

typedef __hip_bfloat16 bf16;
typedef __attribute__((ext_vector_type(8))) short short8v;   // 8 bf16 (4 VGPRs)
typedef __attribute__((ext_vector_type(16))) float f32x16;   // MFMA 32x32 acc

// ---------------- device-global scratch (no d_ws dependence) ----------------
// NOTE: never pass these as host-side kernel args (host shadow symbol ->
// garbage device pointer -> aperture fault).
// NOTE2: bulk fp32 atomicAdd to HBM ~775 GB/s RMW-bound; split-K reductions
// use non-atomic partials + a plain-store full reduction.
// NOTE3: same-line atomic cost scales with INSTRUCTION count, not lane count.
// NOTE4 (round-1): fp32 SGEMM tiling is LDS-pipe-bound; bf16 hi/lo-split MFMA
// (3x v_mfma_f32_32x32x16_bf16) fixed it (91->46us).
// NOTE5 (round-3): tree-gather kernels are LOCALITY-bound, not TLP-bound:
// 32 consecutive columns share ~13/16 ancestors; keep 32-col blocks.
// NOTE6 (round-4): k_atb3 46us = partial-RT + mat=2 gather latency.
// NOTE7 (round-5): KS 64 halved grid (Occ 19%); b64 staging at 80B stride =
// 245k bank conflicts. TLP structure > byte savings; 80B-stride LDS is
// conflict-free ONLY for 16B accesses.
// NOTE8 (round-6): k_logits latency chains fixed by register hoist + fusion
// with BW-bound hx blocks (267->245us).
// NOTE9/10: VGPR 68 > 64-cliff halves waves/SIMD (Occ 18%). scanC_S depth
// 32->8 is a clear win.
// NOTE11 (round-10/11): per-thread serial dtype probe cost 45us in k_trans2.
// x-side vectorized (float4/ushort4).
// NOTE12 (round-12): atb3 software-pipeline NEUTRAL -> reverted.
// NOTE13 (round-13): k_zero fused into k_trans2 (wave-parallel probe).
// NOTE15 (round-14): redundant recompute is only free when its critical path
// is FLAT (runtime-trip chunk-prefix loop = latency*depth -> 47us). Reverted.
// NOTE16 (round-16): round-15 counters caught k_hxlg at VGPR=68/Occ 18%/56us
// -- the 4-col hoist is OVER the 64-VGPR cliff (NOTE10). Round-10's 2-col
// variant measured <44us (its total regression was the trans2-probe
// confound). Logits path -> 2-col hoist (ev[2][16], 32 gathers in flight).
__device__ __align__(16) float g_lxT[(size_t)DD * NB];   // log(x+1), (D x B)
__device__ __align__(16) float g_etaT[(size_t)DM1 * NB]; // eta^T (D-1 x B)
__device__ unsigned short g_etaTb[(size_t)DM1 * NB];     // bf16 copy (gathers)
__device__ __align__(16) float g_hxT[(size_t)DM1 * NB];  // hx^T (D-1 x B)
__device__ __align__(16) float g_S[(size_t)(DD + 1) * NB];   // prefix sums of lx
__device__ __align__(16) float g_part[SCB * NB];         // scan chunk partials
__device__ __align__(16) float g_p0[SCB * NB];           // sumx partials
__device__ __align__(16) float g_p1[SCB * NB];           // sum log(x!) partials
__device__ __align__(16) float g_p2[SCB * NB];           // eta^2 partials
__device__ __align__(16) float g_pc[(size_t)KS * 49152]; // GEMM partials (25 MB)
__device__ __align__(16) float g_zT[16384];              // z_mean^T (K x B)
__device__ __align__(16) float g_WtW[16384];
__device__ __align__(16) float g_e0[16384];              // eta @ dec_w (B x K)
__device__ float g_S1[NB], g_S2[NB], g_sumx[NB], g_slg[NB], g_quad1[NB], g_q2[NB];
__device__ float g_tr[4];
__device__ int g_f32flag;                   // 1: float inputs are f32; 0: bf16
__device__ int g_rlo[DM1], g_rmid[DM1], g_rhi[DM1];
__device__ float g_ra[DM1], g_rb[DM1];
__device__ int g_ccnt[DD];                               // per-column nnz
__device__ int g_crow[(size_t)DD * CMAX];                // per-column row ids
__device__ __align__(16) float g_cval[(size_t)DD * CMAX];// per-column values

// log(n!) for n = 0..23
__device__ __constant__ float c_lgf[24] = {
  0.f, 0.f, 0.6931471806f, 1.7917594692f, 3.1780538303f, 4.7874917428f,
  6.5792512120f, 8.5251613611f, 10.6046029027f, 12.8018274801f,
  15.1044125731f, 17.5023078459f, 19.9872144957f, 22.5521638531f,
  25.1912211827f, 27.8992713838f, 30.6718601061f, 33.5050734501f,
  36.3954452081f, 39.3398841872f, 42.3356164608f, 45.3801388985f,
  48.4711813518f, 51.6066755678f};

__device__ __forceinline__ float b2f(bf16 v) { return __bfloat162float(v); }

__device__ __forceinline__ float wave_red_sum(float v) {
#pragma unroll
  for (int off = 32; off > 0; off >>= 1) v += __shfl_down(v, off, 64);
  return v;
}

__device__ __forceinline__ float load_in(const void* src, size_t idx, int f32) {
  return f32 ? ((const float*)src)[idx] : b2f(((const bf16*)src)[idx]);
}

__device__ __forceinline__ int lbound(const int* a, int n, int key) {
  int lo = 0, hi = n;
  while (lo < hi) { int m = (lo + hi) >> 1; if (a[m] < key) lo = m + 1; else hi = m; }
  return lo;
}

// f32 -> bf16 bits, round-to-nearest-even
__device__ __forceinline__ unsigned short f2bf(float f) {
  unsigned u = __float_as_uint(f);
  unsigned r = (u + 0x7fffu + ((u >> 16) & 1u)) >> 16;
  return (unsigned short)r;
}

// ------- fused: zero-init | transpose (B x N) -> fp32 (N x B) + partials ----
// Wave-parallel dtype probe (NOTE13): lane l checks probe value l; __all
// gives every wave the block-uniform answer at the cost of 1 load + 1 ballot.
// Zero-init work (g_cval etc.) is spread over the first 1250 linear blocks.
// blocks x<SCB: x path (vectorized, NOTE11). x>=SCB: eta path (NOTE12).
__global__ __launch_bounds__(256)
void k_trans2(const void* __restrict__ xsrc, const void* __restrict__ esrc) {
  int tx = threadIdx.x, ty = threadIdx.y;   // (32, 8)
  int t = ty * 32 + tx;                     // 0..255
  // wave-parallel dtype probe
  float pv = ((const float*)xsrc)[t & 63];
  int f32 = __all(pv >= 0.f && pv < 20.5f && floorf(pv) == pv) ? 1 : 0;
  // fused zero-init (linear block id over (x,y) grid)
  int lb = (int)blockIdx.x * 4 + (int)blockIdx.y;
  int zi = lb * 256 + t;
  if (zi < DD * CMAX) g_cval[zi] = 0.f;     // stale g_crow stays in-bounds
  if (zi < DD) g_ccnt[zi] = 0;
  if (zi < NB) { g_S1[zi] = 0.f; g_S2[zi] = 0.f; }
  if (zi < 4) g_tr[zi] = 0.f;
  if (zi == 0) g_f32flag = f32;             // for later kernels

  if ((int)blockIdx.x < SCB) {
    __shared__ float tileT[32][33];     // [c_local][b_local]
    int bx = blockIdx.x;
    int c0 = bx * 32, b0 = blockIdx.y * 32;
    int row = t >> 3;                   // b_local 0..31
    int coff = (t & 7) * 4;             // c_local base
    float v4[4];
    if (f32) {
      float4 vv = *(const float4*)((const float*)xsrc
                    + (size_t)(b0 + row) * DD + c0 + coff);
      v4[0] = vv.x; v4[1] = vv.y; v4[2] = vv.z; v4[3] = vv.w;
    } else {
      ushort4 uu = *(const ushort4*)((const unsigned short*)xsrc
                    + (size_t)(b0 + row) * DD + c0 + coff);
      v4[0] = __uint_as_float((unsigned)uu.x << 16);
      v4[1] = __uint_as_float((unsigned)uu.y << 16);
      v4[2] = __uint_as_float((unsigned)uu.z << 16);
      v4[3] = __uint_as_float((unsigned)uu.w << 16);
    }
    float r0 = 0.f, r1 = 0.f, r2 = 0.f;
#pragma unroll
    for (int j = 0; j < 4; j++) {
      float v = v4[j];
      float lx = logf(v + 1.0f);
      tileT[coff + j][row] = lx;        // banks: (4k+row) mod 32 -> <=2-way
      r0 += v;
      int ix = (int)(v + 0.5f);
      r1 += (ix < 24) ? c_lgf[ix] : lgammaf(v + 1.0f);
      r2 += lx;
    }
#pragma unroll
    for (int off = 4; off > 0; off >>= 1) {
      r0 += __shfl_down(r0, off, 8);
      r1 += __shfl_down(r1, off, 8);
      r2 += __shfl_down(r2, off, 8);
    }
    if ((t & 7) == 0) {
      size_t o = (size_t)bx * NB + (b0 + row);
      g_p0[o] = r0; g_p1[o] = r1; g_part[o] = r2;
    }
    __syncthreads();
    int cc = t >> 3, boff = (t & 7) * 4;
    float4 w = make_float4(tileT[cc][boff], tileT[cc][boff + 1],
                           tileT[cc][boff + 2], tileT[cc][boff + 3]);
    *(float4*)(g_lxT + (size_t)(c0 + cc) * NB + b0 + boff) = w;
    return;
  }
  // ---- eta path (vectorized, unaligned-safe; NOTE12) ----
  __shared__ float tileT[32][33];
  int bx = (int)blockIdx.x - SCB;
  int c0 = bx * 32, b0 = blockIdx.y * 32;
  int row = t >> 3;                   // b_local 0..31
  int coff = (t & 7) * 4;
  int c = c0 + coff;
  float v4[4];
  if (c + 3 < DM1) {
    if (f32) {
      float tmp[4];
      __builtin_memcpy(tmp, (const float*)esrc + (size_t)(b0 + row) * DM1 + c, 16);
#pragma unroll
      for (int j = 0; j < 4; j++) v4[j] = tmp[j];
    } else {
      unsigned short tmp[4];
      __builtin_memcpy(tmp, (const bf16*)esrc + (size_t)(b0 + row) * DM1 + c, 8);
#pragma unroll
      for (int j = 0; j < 4; j++) v4[j] = __uint_as_float((unsigned)tmp[j] << 16);
    }
  } else {
#pragma unroll
    for (int j = 0; j < 4; j++) {
      int cj = c + j;
      v4[j] = (cj < DM1) ? load_in(esrc, (size_t)(b0 + row) * DM1 + cj, f32) : 0.f;
    }
  }
  float r0 = 0.f;
#pragma unroll
  for (int j = 0; j < 4; j++) {
    float v = v4[j];
    tileT[coff + j][row] = v;
    r0 += v * v;
  }
#pragma unroll
  for (int off = 4; off > 0; off >>= 1) r0 += __shfl_down(r0, off, 8);
  if ((t & 7) == 0) g_p2[(size_t)bx * NB + (b0 + row)] = r0;
  __syncthreads();
  int cc = t >> 3, boff = (t & 7) * 4;
  int cg = c0 + cc;
  if (cg < DM1) {
    float4 w = make_float4(tileT[cc][boff], tileT[cc][boff + 1],
                           tileT[cc][boff + 2], tileT[cc][boff + 3]);
    *(float4*)(g_etaT + (size_t)cg * NB + b0 + boff) = w;
    ushort4 wb;
    wb.x = f2bf(w.x); wb.y = f2bf(w.y); wb.z = f2bf(w.z); wb.w = f2bf(w.w);
    *(ushort4*)(g_etaTb + (size_t)cg * NB + b0 + boff) = wb;
  }
}

// ---- fused aux pass: CSC build | row geometry | scanB (all post-trans2) ----
__global__ __launch_bounds__(256)
void k_aux(const int* __restrict__ rows, const int* __restrict__ cols,
           const void* __restrict__ vals, int nnz, int nbc, int nbr) {
  int f32 = g_f32flag;
  int bxx = blockIdx.x;
  if (bxx < nbc) {
    int j = bxx * 256 + threadIdx.x;
    if (j >= nnz) return;
    int c = cols[j];
    int slot = atomicAdd(&g_ccnt[c], 1);
    if (slot < CMAX) {
      g_crow[(size_t)c * CMAX + slot] = rows[j];
      g_cval[(size_t)c * CMAX + slot] = load_in(vals, j, f32);
    }
    return;
  }
  if (bxx < nbc + nbr) {
    int r = (bxx - nbc) * 256 + threadIdx.x;
    if (r >= DM1) return;
    int s = lbound(rows, nnz, r), e = lbound(rows, nnz, r + 1);
    int lo = cols[s], hi = cols[e - 1] + 1;
    int lo_i = s, hi_i = e - 1;            // vals[s] > 0, vals[e-1] < 0
    while (hi_i - lo_i > 1) {
      int m = (lo_i + hi_i) >> 1;
      if (load_in(vals, m, f32) < 0.f) hi_i = m; else lo_i = m;
    }
    g_rlo[r] = lo; g_rmid[r] = lo + (hi_i - s); g_rhi[r] = hi;
    g_ra[r] = load_in(vals, s, f32);
    g_rb[r] = load_in(vals, e - 1, f32);
    return;
  }
  // ---- scanB ----
  __shared__ float sc[256];
  int b = bxx - nbc - nbr;      // 0..127
  int t = threadIdx.x;          // chunks 3t..3t+2
  float v[3];
  float s = 0.f;
#pragma unroll
  for (int q = 0; q < 3; q++) {
    int idx = t * 3 + q;
    v[q] = (idx < SCB) ? g_part[(size_t)idx * NB + b] : 0.f;
    s += v[q];
  }
  sc[t] = s;
  __syncthreads();
  for (int d = 1; d < 256; d <<= 1) {
    float add = (t >= d) ? sc[t - d] : 0.f;
    __syncthreads();
    sc[t] += add;
    __syncthreads();
  }
  float run = (t == 0) ? 0.f : sc[t - 1];
#pragma unroll
  for (int q = 0; q < 3; q++) {
    int idx = t * 3 + q;
    if (idx < SCB) {
      float tmp = v[q];
      g_part[(size_t)idx * NB + b] = run;
      run += tmp;
    }
  }
  float s0 = 0.f, s1 = 0.f, s2 = 0.f;
  for (int idx = t; idx < SCB; idx += 256) {
    size_t o = (size_t)idx * NB + b;
    s0 += g_p0[o];
    s1 += g_p1[o];
    s2 += g_p2[o];
  }
  __syncthreads();
  sc[t] = s0;
  __syncthreads();
  for (int d = 128; d > 0; d >>= 1) { if (t < d) sc[t] += sc[t + d]; __syncthreads(); }
  if (t == 0) g_sumx[b] = sc[0];
  __syncthreads();
  sc[t] = s1;
  __syncthreads();
  for (int d = 128; d > 0; d >>= 1) { if (t < d) sc[t] += sc[t + d]; __syncthreads(); }
  if (t == 0) g_slg[b] = sc[0];
  __syncthreads();
  sc[t] = s2;
  __syncthreads();
  for (int d = 128; d > 0; d >>= 1) { if (t < d) sc[t] += sc[t + d]; __syncthreads(); }
  if (t == 0) g_quad1[b] = sc[0];
}

// exclusive prefix S[c] of lx; serial depth 8 (NOTE9). 512 threads:
// (kg 0..3) x (b 0..127); each thread loads its 8 lx up-front, LDS combine
// gives the per-(kg,b) base, then an 8-step register walk writes S.
__global__ __launch_bounds__(512)
void k_scanC_S() {
  __shared__ float ksum[4][128];
  int j = blockIdx.x;
  int t = threadIdx.x;
  int b = t & 127, kg = t >> 7;
  int c0 = j * SCH + kg * 8;          // SCH==32 divides DD exactly
  float lv[8];
#pragma unroll
  for (int q = 0; q < 8; q++)
    lv[q] = g_lxT[(size_t)(c0 + q) * NB + b];
  float lsum = 0.f;
#pragma unroll
  for (int q = 0; q < 8; q++) lsum += lv[q];
  ksum[kg][b] = lsum;
  __syncthreads();
  float base = g_part[(size_t)j * NB + b];
  for (int g = 0; g < kg; g++) base += ksum[g][b];
#pragma unroll
  for (int q = 0; q < 8; q++) {
    g_S[(size_t)(c0 + q) * NB + b] = base;
    base += lv[q];
  }
  if (j == SCB - 1 && kg == 3) g_S[(size_t)DD * NB + b] = base;
}

// ---- fused hx materialization + logits/softmax -----------------------------
// blocks [0,SCB): hx[r][b] coalesced from S + row geometry (BW-bound).
// blocks [SCB,2*SCB): logits CSC gather + softmax accum (latency-bound),
// 2-col register hoist (NOTE16: VGPR <= 64-cliff -> 8 waves/SIMD).
__global__ __launch_bounds__(512)
void k_hxlg() {
  int t = threadIdx.x;
  if ((int)blockIdx.x < SCB) {
    __shared__ int slo[32], smid[32], shi[32];
    __shared__ float sa[32], sb[32];
    int r0 = blockIdx.x * 32;
    if (t < 32) {
      int r = r0 + t;
      if (r < DM1) {
        slo[t] = g_rlo[r]; smid[t] = g_rmid[r]; shi[t] = g_rhi[r];
        sa[t] = g_ra[r];   sb[t] = g_rb[r];
      }
    }
    __syncthreads();
    int b = t & 127, g = t >> 7;      // 4 groups x 8 rows
#pragma unroll
    for (int q = 0; q < 8; q++) {
      int rr = g * 8 + q;
      int r = r0 + rr;
      if (r >= DM1) break;
      float sl = g_S[(size_t)slo[rr]  * NB + b];
      float sm = g_S[(size_t)smid[rr] * NB + b];
      float sh = g_S[(size_t)shi[rr]  * NB + b];
      g_hxT[(size_t)r * NB + b] = sa[rr] * (sm - sl) + sb[rr] * (sh - sm);
    }
    return;
  }
  // ---- logits (2-col hoist, NOTE16) ----
  __shared__ int   sr[32][CMAX];
  __shared__ float sv[32][CMAX];
  __shared__ float s1s[4][128], s2s[4][128];
  int c0 = ((int)blockIdx.x - SCB) * 32;
  {
    int cc = t >> 4, l = t & 15;   // 512 threads = 32x16 exactly
    sr[cc][l] = g_crow[(size_t)(c0 + cc) * CMAX + l];
    sv[cc][l] = g_cval[(size_t)(c0 + cc) * CMAX + l];
  }
  __syncthreads();
  int b = t & 127;
  int qg = t >> 7;                 // 0..3
  float s1 = 0.f, s2 = 0.f;
#pragma unroll
  for (int q = 0; q < 8; q += 2) {
    int cc = qg * 8 + q;
    unsigned short ev[2][CMAX];    // 32 independent gathers in flight
#pragma unroll
    for (int j = 0; j < 2; j++)
#pragma unroll
      for (int l = 0; l < CMAX; l++)
        ev[j][l] = g_etaTb[(size_t)sr[cc + j][l] * NB + b];
    float lxv[2];
#pragma unroll
    for (int j = 0; j < 2; j++)
      lxv[j] = g_lxT[(size_t)(c0 + cc + j) * NB + b];
#pragma unroll
    for (int j = 0; j < 2; j++) {
      float lg = 0.f;
#pragma unroll
      for (int l = 0; l < CMAX; l++)
        lg += sv[cc + j][l] * __uint_as_float((unsigned)ev[j][l] << 16);
      s1 += expf(lg);
      s2 += (expf(lxv[j]) - 1.0f) * lg;
    }
  }
  s1s[qg][b] = s1;
  s2s[qg][b] = s2;
  __syncthreads();
  if (qg == 0) {
    atomicAdd(&g_S1[b], s1s[0][b] + s1s[1][b] + s1s[2][b] + s1s[3][b]);
    atomicAdd(&g_S2[b], s2s[0][b] + s2s[1][b] + s2s[2][b] + s2s[3][b]);
  }
}

// ---- fused triple GEMM via bf16 hi/lo-split MFMA (round-8/11 exact) --------
// grid (KS, 6): y = mat*2 + jhalf. Block: C tile 128i x 64j, 512 threads =
// 8 waves of one 32x32 MFMA tile each. BK=32 staged per round (b128-only LDS
// at 80B stride -> 0 bank conflicts; NOTE7). Non-pipelined (NOTE12).
// mat 0: A=dec, B=dec -> WtW   mat 1: A=etaT, B=dec -> e0
// mat 2: A=g_hxT (precomputed), B=enc -> z
__global__ __launch_bounds__(512)
void k_atb3(const void* __restrict__ dec, const void* __restrict__ enc) {
  __shared__ unsigned short Ah[128][40], Al[128][40];
  __shared__ unsigned short Bh[64][40],  Bl[64][40];
  int f32 = g_f32flag;
  int mat = blockIdx.y >> 1;
  int j0 = (blockIdx.y & 1) * 64;
  int ks = blockIdx.x * GCH;
  int ke = min(ks + GCH, DM1);
  int t = threadIdx.x;
  int lane = t & 63;
  int w = t >> 6;            // wave 0..7
  int wi = (w >> 1) * 32;    // row tile base
  int wj = (w & 1) * 32;     // col tile base (within 64)
  int ai = t & 127;          // A stage: column i
  int akg = t >> 7;          // A stage: k-group (0..3), 8 k each
  int bj = t & 63;           // B stage: column j (threads 0..255)
  int bkg = (t >> 6) & 3;    // B stage: k-group

  f32x16 acc;
#pragma unroll
  for (int r = 0; r < 16; r++) acc[r] = 0.f;

  for (int kb = ks; kb < ke; kb += 32) {
    float av[8];
#pragma unroll
    for (int q = 0; q < 8; q++) {
      int k = kb + akg * 8 + q;
      float v = 0.f;
      if (k < ke) {
        if (mat == 2)      v = g_hxT[(size_t)k * NB + ai];
        else if (mat == 1) v = g_etaT[(size_t)k * NB + ai];
        else               v = load_in(dec, (size_t)k * 128 + ai, f32);
      }
      av[q] = v;
    }
    float bv[8];
    if (t < 256) {
#pragma unroll
      for (int q = 0; q < 8; q++) {
        int k = kb + bkg * 8 + q;
        float v = 0.f;
        if (k < ke) {
          if (mat == 2) v = load_in(enc, (size_t)(j0 + bj) * DM1 + k, f32);
          else          v = load_in(dec, (size_t)k * 128 + j0 + bj, f32);
        }
        bv[q] = v;
      }
    }
    __syncthreads();   // previous round's fragment reads complete
    {
      short8v h8, l8;
#pragma unroll
      for (int q = 0; q < 8; q++) {
        unsigned short h = f2bf(av[q]);
        float hf = __uint_as_float((unsigned)h << 16);
        h8[q] = (short)h;
        l8[q] = (short)f2bf(av[q] - hf);
      }
      *(short8v*)&Ah[ai][akg * 8] = h8;
      *(short8v*)&Al[ai][akg * 8] = l8;
    }
    if (t < 256) {
      short8v h8, l8;
#pragma unroll
      for (int q = 0; q < 8; q++) {
        unsigned short h = f2bf(bv[q]);
        float hf = __uint_as_float((unsigned)h << 16);
        h8[q] = (short)h;
        l8[q] = (short)f2bf(bv[q] - hf);
      }
      *(short8v*)&Bh[bj][bkg * 8] = h8;
      *(short8v*)&Bl[bj][bkg * 8] = l8;
    }
    __syncthreads();   // tile ready
#pragma unroll
    for (int s = 0; s < 2; s++) {
      int k0 = s * 16 + (lane >> 5) * 8;
      int ar = wi + (lane & 31);
      int bc = wj + (lane & 31);
      short8v a_h = *(const short8v*)&Ah[ar][k0];
      short8v a_l = *(const short8v*)&Al[ar][k0];
      short8v b_h = *(const short8v*)&Bh[bc][k0];
      short8v b_l = *(const short8v*)&Bl[bc][k0];
      acc = __builtin_amdgcn_mfma_f32_32x32x16_bf16(a_h, b_h, acc, 0, 0, 0);
      acc = __builtin_amdgcn_mfma_f32_32x32x16_bf16(a_l, b_h, acc, 0, 0, 0);
      acc = __builtin_amdgcn_mfma_f32_32x32x16_bf16(a_h, b_l, acc, 0, 0, 0);
    }
  }
  // C/D layout: col=lane&31, row=(r&3)+8*(r>>2)+4*(lane>>5)
  float* dst = g_pc + (size_t)blockIdx.x * 49152 + mat * 16384;
  int col = j0 + wj + (lane & 31);
#pragma unroll
  for (int r = 0; r < 16; r++) {
    int row = wi + (r & 3) + 8 * (r >> 2) + 4 * (lane >> 5);
    dst[row * 128 + col] = acc[r];
  }
}

// full reduction of KS partials; PLAIN stores (one writer per element).
// 768 blocks (round-8 exact), 4 threads per element + LDS combine.
__global__ __launch_bounds__(256)
void k_red3() {
  __shared__ float sh[256];
  int t = threadIdx.x;
  int e = blockIdx.x * 64 + (t & 63);
  int sg = t >> 6;               // 0..3
  float acc = 0.f;
#pragma unroll 8
  for (int s = sg * 32; s < sg * 32 + 32; s++)
    acc += g_pc[(size_t)s * 49152 + e];
  sh[t] = acc;
  __syncthreads();
  if (t < 64) {
    float v = sh[t] + sh[t + 64] + sh[t + 128] + sh[t + 192];
    int g = blockIdx.x * 64 + t;
    int m = g >> 14, e2 = g & 16383;
    if (m == 0) g_WtW[e2] = v;
    else if (m == 1) g_e0[e2] = v;
    else g_zT[(e2 & 127) * 128 + (e2 >> 7)] = v;   // zT[h][b]
  }
}

// ---- merged p2t (traces of P) + upost (Neumann quad terms) -----------------
__global__ __launch_bounds__(128)
void k_pu(const void* __restrict__ logvars, const void* __restrict__ lsq) {
  __shared__ float sh0[128], sh1[128], sh2[128], sh3[128], sh4[128], sh5[128];
  __shared__ float sds[128];
  int j = threadIdx.x;
  int f32 = g_f32flag;
  float invvar = expf(-load_in(lsq, 0, f32));
  sds[j] = expf(0.5f * load_in(logvars, j, f32));
  __syncthreads();
  if ((int)blockIdx.x < 128) {
    int i = blockIdx.x;
    float sdj = sds[j];
    float p = sds[i] * sdj * g_WtW[i * 128 + j] * invvar;
    sh0[j] = p;
    __syncthreads();
    float acc = 0.f;
    for (int k = 0; k < 128; k++)
      acc += sh0[k] * (sds[k] * sdj * g_WtW[k * 128 + j] * invvar);
    float v1 = wave_red_sum((i == j) ? p : 0.f);
    float v2 = wave_red_sum(p * p);
    float v3 = wave_red_sum(p * acc);
    float v4 = wave_red_sum(acc * acc);
    if ((j & 63) == 0) {
      atomicAdd(&g_tr[0], v1);
      atomicAdd(&g_tr[1], v2);
      atomicAdd(&g_tr[2], v3);
      atomicAdd(&g_tr[3], v4);
    }
  } else {
    int b = blockIdx.x - 128, k = j;
    float sdk = sds[k];
    sh0[k] = g_zT[(size_t)k * 128 + b];   // z[b, k]
    __syncthreads();
    float e0k = g_e0[b * 128 + k];
    float zWk = 0.f;
    for (int m = 0; m < 128; m++) zWk += sh0[m] * g_WtW[m * 128 + k];
    float u = (e0k - zWk) * sdk;
    sh1[k] = u;
    sh5[k] = sh0[k] * (zWk - 2.f * e0k);
    __syncthreads();
    float v1 = 0.f;
    for (int m = 0; m < 128; m++) v1 += sds[m] * g_WtW[m * 128 + k] * sh1[m];
    v1 *= sdk * invvar;
    sh2[k] = v1;
    __syncthreads();
    float v2 = 0.f;
    for (int m = 0; m < 128; m++) v2 += sds[m] * g_WtW[m * 128 + k] * sh2[m];
    v2 *= sdk * invvar;
    sh3[k] = v2;
    __syncthreads();
    float v3 = 0.f;
    for (int m = 0; m < 128; m++) v3 += sds[m] * g_WtW[m * 128 + k] * sh3[m];
    v3 *= sdk * invvar;
    sh4[k] = u * (u - v1 + v2 - v3);
    __syncthreads();
    for (int s = 64; s > 0; s >>= 1) {
      if (k < s) { sh4[k] += sh4[k + s]; sh5[k] += sh5[k + s]; }
      __syncthreads();
    }
    if (k == 0) {
      g_q2[b] = sh4[0];
      g_quad1[b] += sh5[0];   // quad1 held sum(eta^2) from scanB
    }
  }
}

// Output dtype: FLOAT32.
__global__ __launch_bounds__(128)
void k_final(const void* __restrict__ lsq, float* __restrict__ out) {
  __shared__ double red[128];
  __shared__ float redz[128];
  int b = threadIdx.x;
  int f32 = g_f32flag;
  float zs = 0.f;
  for (int i = b; i < 16384; i += 128) { float v = g_zT[i]; zs += v * v; }
  redz[b] = zs;
  const double LOG2PI = 1.837877066409345483560659472811;
  float lsqv = load_in(lsq, 0, f32);
  double var = exp((double)lsqv);
  double lse = log((double)g_S1[b]);
  double sumx = (double)g_sumx[b];
  double t1 = lgamma(sumx + 1.0) - (double)g_slg[b];
  double mult_b = t1 + (double)g_S2[b] - sumx * lse;
  double logdetM = (double)g_tr[0] - 0.5 * (double)g_tr[1]
                 + (1.0 / 3.0) * (double)g_tr[2] - 0.25 * (double)g_tr[3];
  double logdet = (double)DM1 * (double)lsqv + logdetM;
  double quad_b = (double)g_quad1[b] / var - (double)g_q2[b] / (var * var);
  double logit_b = -0.5 * ((double)DM1 * LOG2PI + logdet + quad_b);
  red[b] = mult_b + logit_b;
  __syncthreads();
  for (int s = 64; s > 0; s >>= 1) {
    if (b < s) { red[b] += red[b + s]; redz[b] += redz[b + s]; }
    __syncthreads();
  }
  if (b == 0) {
    double ml = red[0] / 128.0;  // mean_b(mult + logit)
    double prior = -0.5 * (double)redz[0] / 16384.0 - 0.5 * LOG2PI;
    out[0] = (float)(-(ml + prior));
  }
}

extern "C" void kernel_launch(void* const* d_in, const int* in_sizes, int n_in,
                              void* d_out, int out_size, void* d_ws, size_t ws_size,
                              hipStream_t stream) {
  const void* x     = d_in[0];
  const int*  rows  = (const int*)d_in[1];
  const int*  cols  = (const int*)d_in[2];
  const void* vals  = d_in[3];
  const void* enc_w = d_in[4];
  const void* dec_w = d_in[5];
  const void* lvars = d_in[6];
  const void* lsq   = d_in[7];
  const void* eta   = d_in[8];
  float* out = (float*)d_out;
  int nnz = in_sizes[1];
  (void)d_ws; (void)ws_size;

  int nbc = (nnz + 255) / 256;
  int nbr = (DM1 + 255) / 256;

  k_trans2<<<dim3(2 * SCB, 4), dim3(32, 8), 0, stream>>>(x, eta);  // + zero/probe
  k_aux<<<nbc + nbr + 128, 256, 0, stream>>>(rows, cols, vals, nnz, nbc, nbr);
  k_scanC_S<<<SCB, 512, 0, stream>>>();                 // S prefix (depth 8)
  k_hxlg<<<2 * SCB, 512, 0, stream>>>();                // hx | logits fused
  k_atb3<<<dim3(KS, 6), 512, 0, stream>>>(dec_w, enc_w);// WtW|e0|z partials (MFMA)
  k_red3<<<768, 256, 0, stream>>>();
  k_pu<<<256, 128, 0, stream>>>(lvars, lsq);            // traces + quad terms
  k_final<<<1, 128, 0, stream>>>(lsq, out);
}

// Round 17
// 223.180 us; speedup vs baseline: 1.1150x; 1.0013x over previous
//
#include <hip/hip_runtime.h>
#include <hip/hip_bf16.h>

#define DD 20000
#define DM1 19999
#define NB 128     // batch
#define SCB 625    // scan chunks (= transpose c-tiles)
#define SCH 32     // per-chunk span (625*32 = 20000)
#define KS 128     // GEMM k-split blocks
#define GCH 157    // GEMM k-chunk span (128*157 >= 19999)
#define CMAX 16    // max nnz per Psi column (balanced tree depth <= 15)

typedef __hip_bfloat16 bf16;
typedef __attribute__((ext_vector_type(8))) short short8v;   // 8 bf16 (4 VGPRs)
typedef __attribute__((ext_vector_type(16))) float f32x16;   // MFMA 32x32 acc

// ---------------- device-global scratch (no d_ws dependence) ----------------
// NOTE: never pass these as host-side kernel args (host shadow symbol ->
// garbage device pointer -> aperture fault).
// NOTE2: bulk fp32 atomicAdd to HBM ~775 GB/s RMW-bound; split-K reductions
// use non-atomic partials + a plain-store full reduction.
// NOTE3: same-line atomic cost scales with INSTRUCTION count, not lane count.
// NOTE4 (round-1): fp32 SGEMM tiling is LDS-pipe-bound; bf16 hi/lo-split MFMA
// (3x v_mfma_f32_32x32x16_bf16) fixed it (91->46us).
// NOTE5 (round-3): tree-gather kernels are LOCALITY-bound, not TLP-bound:
// 32 consecutive columns share ~13/16 ancestors; keep 32-col blocks.
// NOTE6 (round-4): k_atb3 46us = partial-RT + mat=2 gather latency.
// NOTE7 (round-5): KS 64 halved grid (Occ 19%); b64 staging at 80B stride =
// 245k bank conflicts. TLP structure > byte savings; 80B-stride LDS is
// conflict-free ONLY for 16B accesses.
// NOTE8 (round-6): k_logits latency chains fixed by register hoist + fusion
// with BW-bound hx blocks (267->245us).
// NOTE9/10: VGPR 68 > 64-cliff halves waves/SIMD. scanC_S depth 32->8 win.
// NOTE11: serial dtype probe cost 45us; x-side vectorized (float4/ushort4).
// NOTE12: atb3 software-pipeline NEUTRAL -> reverted.
// NOTE13: k_zero fused into k_trans2 (wave-parallel probe: 1 load + __all).
// NOTE15: redundant recompute only free when critical path is FLAT.
// NOTE16: k_hxlg 4-col hoist was over the 64-VGPR cliff; 2-col fixed
// (56->\u226440us). 223.5us best.
// NOTE17 (round-17): g_etaT f32 dropped -- only consumer was atb3 mat1, and
// eta is already bf16 in the logits path. mat1 reads g_etaTb; its A-lo is
// identically 0 so the a_l MFMA is skipped (wave-uniform branch). Saves
// ~10MB write + ~10MB read + 1/3 of mat1 MFMAs. e0 perturbation ~2^-9 rel
// on ~1e-6-magnitude quad terms vs 3.7e4 logit term: << 1 output ulp.
__device__ __align__(16) float g_lxT[(size_t)DD * NB];   // log(x+1), (D x B)
__device__ unsigned short g_etaTb[(size_t)DM1 * NB];     // eta^T bf16 (all uses)
__device__ __align__(16) float g_hxT[(size_t)DM1 * NB];  // hx^T (D-1 x B)
__device__ __align__(16) float g_S[(size_t)(DD + 1) * NB];   // prefix sums of lx
__device__ __align__(16) float g_part[SCB * NB];         // scan chunk partials
__device__ __align__(16) float g_p0[SCB * NB];           // sumx partials
__device__ __align__(16) float g_p1[SCB * NB];           // sum log(x!) partials
__device__ __align__(16) float g_p2[SCB * NB];           // eta^2 partials
__device__ __align__(16) float g_pc[(size_t)KS * 49152]; // GEMM partials (25 MB)
__device__ __align__(16) float g_zT[16384];              // z_mean^T (K x B)
__device__ __align__(16) float g_WtW[16384];
__device__ __align__(16) float g_e0[16384];              // eta @ dec_w (B x K)
__device__ float g_S1[NB], g_S2[NB], g_sumx[NB], g_slg[NB], g_quad1[NB], g_q2[NB];
__device__ float g_tr[4];
__device__ int g_f32flag;                   // 1: float inputs are f32; 0: bf16
__device__ int g_rlo[DM1], g_rmid[DM1], g_rhi[DM1];
__device__ float g_ra[DM1], g_rb[DM1];
__device__ int g_ccnt[DD];                               // per-column nnz
__device__ int g_crow[(size_t)DD * CMAX];                // per-column row ids
__device__ __align__(16) float g_cval[(size_t)DD * CMAX];// per-column values

// log(n!) for n = 0..23
__device__ __constant__ float c_lgf[24] = {
  0.f, 0.f, 0.6931471806f, 1.7917594692f, 3.1780538303f, 4.7874917428f,
  6.5792512120f, 8.5251613611f, 10.6046029027f, 12.8018274801f,
  15.1044125731f, 17.5023078459f, 19.9872144957f, 22.5521638531f,
  25.1912211827f, 27.8992713838f, 30.6718601061f, 33.5050734501f,
  36.3954452081f, 39.3398841872f, 42.3356164608f, 45.3801388985f,
  48.4711813518f, 51.6066755678f};

__device__ __forceinline__ float b2f(bf16 v) { return __bfloat162float(v); }

__device__ __forceinline__ float wave_red_sum(float v) {
#pragma unroll
  for (int off = 32; off > 0; off >>= 1) v += __shfl_down(v, off, 64);
  return v;
}

__device__ __forceinline__ float load_in(const void* src, size_t idx, int f32) {
  return f32 ? ((const float*)src)[idx] : b2f(((const bf16*)src)[idx]);
}

__device__ __forceinline__ int lbound(const int* a, int n, int key) {
  int lo = 0, hi = n;
  while (lo < hi) { int m = (lo + hi) >> 1; if (a[m] < key) lo = m + 1; else hi = m; }
  return lo;
}

// f32 -> bf16 bits, round-to-nearest-even
__device__ __forceinline__ unsigned short f2bf(float f) {
  unsigned u = __float_as_uint(f);
  unsigned r = (u + 0x7fffu + ((u >> 16) & 1u)) >> 16;
  return (unsigned short)r;
}

// ------- fused: zero-init | transpose (B x N) -> fp32 (N x B) + partials ----
// Wave-parallel dtype probe (NOTE13): lane l checks probe value l; __all
// gives every wave the block-uniform answer at the cost of 1 load + 1 ballot.
// Zero-init work (g_cval etc.) is spread over the first 1250 linear blocks.
// blocks x<SCB: x path (vectorized, NOTE11). x>=SCB: eta path (bf16-only
// output, NOTE17).
__global__ __launch_bounds__(256)
void k_trans2(const void* __restrict__ xsrc, const void* __restrict__ esrc) {
  int tx = threadIdx.x, ty = threadIdx.y;   // (32, 8)
  int t = ty * 32 + tx;                     // 0..255
  // wave-parallel dtype probe
  float pv = ((const float*)xsrc)[t & 63];
  int f32 = __all(pv >= 0.f && pv < 20.5f && floorf(pv) == pv) ? 1 : 0;
  // fused zero-init (linear block id over (x,y) grid)
  int lb = (int)blockIdx.x * 4 + (int)blockIdx.y;
  int zi = lb * 256 + t;
  if (zi < DD * CMAX) g_cval[zi] = 0.f;     // stale g_crow stays in-bounds
  if (zi < DD) g_ccnt[zi] = 0;
  if (zi < NB) { g_S1[zi] = 0.f; g_S2[zi] = 0.f; }
  if (zi < 4) g_tr[zi] = 0.f;
  if (zi == 0) g_f32flag = f32;             // for later kernels

  if ((int)blockIdx.x < SCB) {
    __shared__ float tileT[32][33];     // [c_local][b_local]
    int bx = blockIdx.x;
    int c0 = bx * 32, b0 = blockIdx.y * 32;
    int row = t >> 3;                   // b_local 0..31
    int coff = (t & 7) * 4;             // c_local base
    float v4[4];
    if (f32) {
      float4 vv = *(const float4*)((const float*)xsrc
                    + (size_t)(b0 + row) * DD + c0 + coff);
      v4[0] = vv.x; v4[1] = vv.y; v4[2] = vv.z; v4[3] = vv.w;
    } else {
      ushort4 uu = *(const ushort4*)((const unsigned short*)xsrc
                    + (size_t)(b0 + row) * DD + c0 + coff);
      v4[0] = __uint_as_float((unsigned)uu.x << 16);
      v4[1] = __uint_as_float((unsigned)uu.y << 16);
      v4[2] = __uint_as_float((unsigned)uu.z << 16);
      v4[3] = __uint_as_float((unsigned)uu.w << 16);
    }
    float r0 = 0.f, r1 = 0.f, r2 = 0.f;
#pragma unroll
    for (int j = 0; j < 4; j++) {
      float v = v4[j];
      float lx = logf(v + 1.0f);
      tileT[coff + j][row] = lx;        // banks: (4k+row) mod 32 -> <=2-way
      r0 += v;
      int ix = (int)(v + 0.5f);
      r1 += (ix < 24) ? c_lgf[ix] : lgammaf(v + 1.0f);
      r2 += lx;
    }
#pragma unroll
    for (int off = 4; off > 0; off >>= 1) {
      r0 += __shfl_down(r0, off, 8);
      r1 += __shfl_down(r1, off, 8);
      r2 += __shfl_down(r2, off, 8);
    }
    if ((t & 7) == 0) {
      size_t o = (size_t)bx * NB + (b0 + row);
      g_p0[o] = r0; g_p1[o] = r1; g_part[o] = r2;
    }
    __syncthreads();
    int cc = t >> 3, boff = (t & 7) * 4;
    float4 w = make_float4(tileT[cc][boff], tileT[cc][boff + 1],
                           tileT[cc][boff + 2], tileT[cc][boff + 3]);
    *(float4*)(g_lxT + (size_t)(c0 + cc) * NB + b0 + boff) = w;
    return;
  }
  // ---- eta path (vectorized; bf16-only output, NOTE17) ----
  __shared__ float tileT[32][33];
  int bx = (int)blockIdx.x - SCB;
  int c0 = bx * 32, b0 = blockIdx.y * 32;
  int row = t >> 3;                   // b_local 0..31
  int coff = (t & 7) * 4;
  int c = c0 + coff;
  float v4[4];
  if (c + 3 < DM1) {
    if (f32) {
      float tmp[4];
      __builtin_memcpy(tmp, (const float*)esrc + (size_t)(b0 + row) * DM1 + c, 16);
#pragma unroll
      for (int j = 0; j < 4; j++) v4[j] = tmp[j];
    } else {
      unsigned short tmp[4];
      __builtin_memcpy(tmp, (const bf16*)esrc + (size_t)(b0 + row) * DM1 + c, 8);
#pragma unroll
      for (int j = 0; j < 4; j++) v4[j] = __uint_as_float((unsigned)tmp[j] << 16);
    }
  } else {
#pragma unroll
    for (int j = 0; j < 4; j++) {
      int cj = c + j;
      v4[j] = (cj < DM1) ? load_in(esrc, (size_t)(b0 + row) * DM1 + cj, f32) : 0.f;
    }
  }
  float r0 = 0.f;
#pragma unroll
  for (int j = 0; j < 4; j++) {
    float v = v4[j];
    tileT[coff + j][row] = v;
    r0 += v * v;
  }
#pragma unroll
  for (int off = 4; off > 0; off >>= 1) r0 += __shfl_down(r0, off, 8);
  if ((t & 7) == 0) g_p2[(size_t)bx * NB + (b0 + row)] = r0;
  __syncthreads();
  int cc = t >> 3, boff = (t & 7) * 4;
  int cg = c0 + cc;
  if (cg < DM1) {
    ushort4 wb;
    wb.x = f2bf(tileT[cc][boff]);
    wb.y = f2bf(tileT[cc][boff + 1]);
    wb.z = f2bf(tileT[cc][boff + 2]);
    wb.w = f2bf(tileT[cc][boff + 3]);
    *(ushort4*)(g_etaTb + (size_t)cg * NB + b0 + boff) = wb;
  }
}

// ---- fused aux pass: CSC build | row geometry | scanB (all post-trans2) ----
__global__ __launch_bounds__(256)
void k_aux(const int* __restrict__ rows, const int* __restrict__ cols,
           const void* __restrict__ vals, int nnz, int nbc, int nbr) {
  int f32 = g_f32flag;
  int bxx = blockIdx.x;
  if (bxx < nbc) {
    int j = bxx * 256 + threadIdx.x;
    if (j >= nnz) return;
    int c = cols[j];
    int slot = atomicAdd(&g_ccnt[c], 1);
    if (slot < CMAX) {
      g_crow[(size_t)c * CMAX + slot] = rows[j];
      g_cval[(size_t)c * CMAX + slot] = load_in(vals, j, f32);
    }
    return;
  }
  if (bxx < nbc + nbr) {
    int r = (bxx - nbc) * 256 + threadIdx.x;
    if (r >= DM1) return;
    int s = lbound(rows, nnz, r), e = lbound(rows, nnz, r + 1);
    int lo = cols[s], hi = cols[e - 1] + 1;
    int lo_i = s, hi_i = e - 1;            // vals[s] > 0, vals[e-1] < 0
    while (hi_i - lo_i > 1) {
      int m = (lo_i + hi_i) >> 1;
      if (load_in(vals, m, f32) < 0.f) hi_i = m; else lo_i = m;
    }
    g_rlo[r] = lo; g_rmid[r] = lo + (hi_i - s); g_rhi[r] = hi;
    g_ra[r] = load_in(vals, s, f32);
    g_rb[r] = load_in(vals, e - 1, f32);
    return;
  }
  // ---- scanB ----
  __shared__ float sc[256];
  int b = bxx - nbc - nbr;      // 0..127
  int t = threadIdx.x;          // chunks 3t..3t+2
  float v[3];
  float s = 0.f;
#pragma unroll
  for (int q = 0; q < 3; q++) {
    int idx = t * 3 + q;
    v[q] = (idx < SCB) ? g_part[(size_t)idx * NB + b] : 0.f;
    s += v[q];
  }
  sc[t] = s;
  __syncthreads();
  for (int d = 1; d < 256; d <<= 1) {
    float add = (t >= d) ? sc[t - d] : 0.f;
    __syncthreads();
    sc[t] += add;
    __syncthreads();
  }
  float run = (t == 0) ? 0.f : sc[t - 1];
#pragma unroll
  for (int q = 0; q < 3; q++) {
    int idx = t * 3 + q;
    if (idx < SCB) {
      float tmp = v[q];
      g_part[(size_t)idx * NB + b] = run;
      run += tmp;
    }
  }
  float s0 = 0.f, s1 = 0.f, s2 = 0.f;
  for (int idx = t; idx < SCB; idx += 256) {
    size_t o = (size_t)idx * NB + b;
    s0 += g_p0[o];
    s1 += g_p1[o];
    s2 += g_p2[o];
  }
  __syncthreads();
  sc[t] = s0;
  __syncthreads();
  for (int d = 128; d > 0; d >>= 1) { if (t < d) sc[t] += sc[t + d]; __syncthreads(); }
  if (t == 0) g_sumx[b] = sc[0];
  __syncthreads();
  sc[t] = s1;
  __syncthreads();
  for (int d = 128; d > 0; d >>= 1) { if (t < d) sc[t] += sc[t + d]; __syncthreads(); }
  if (t == 0) g_slg[b] = sc[0];
  __syncthreads();
  sc[t] = s2;
  __syncthreads();
  for (int d = 128; d > 0; d >>= 1) { if (t < d) sc[t] += sc[t + d]; __syncthreads(); }
  if (t == 0) g_quad1[b] = sc[0];
}

// exclusive prefix S[c] of lx; serial depth 8 (NOTE9). 512 threads:
// (kg 0..3) x (b 0..127); each thread loads its 8 lx up-front, LDS combine
// gives the per-(kg,b) base, then an 8-step register walk writes S.
__global__ __launch_bounds__(512)
void k_scanC_S() {
  __shared__ float ksum[4][128];
  int j = blockIdx.x;
  int t = threadIdx.x;
  int b = t & 127, kg = t >> 7;
  int c0 = j * SCH + kg * 8;          // SCH==32 divides DD exactly
  float lv[8];
#pragma unroll
  for (int q = 0; q < 8; q++)
    lv[q] = g_lxT[(size_t)(c0 + q) * NB + b];
  float lsum = 0.f;
#pragma unroll
  for (int q = 0; q < 8; q++) lsum += lv[q];
  ksum[kg][b] = lsum;
  __syncthreads();
  float base = g_part[(size_t)j * NB + b];
  for (int g = 0; g < kg; g++) base += ksum[g][b];
#pragma unroll
  for (int q = 0; q < 8; q++) {
    g_S[(size_t)(c0 + q) * NB + b] = base;
    base += lv[q];
  }
  if (j == SCB - 1 && kg == 3) g_S[(size_t)DD * NB + b] = base;
}

// ---- fused hx materialization + logits/softmax -----------------------------
// blocks [0,SCB): hx[r][b] coalesced from S + row geometry (BW-bound).
// blocks [SCB,2*SCB): logits CSC gather + softmax accum (latency-bound),
// 2-col register hoist (NOTE16: VGPR <= 64-cliff -> 8 waves/SIMD).
__global__ __launch_bounds__(512)
void k_hxlg() {
  int t = threadIdx.x;
  if ((int)blockIdx.x < SCB) {
    __shared__ int slo[32], smid[32], shi[32];
    __shared__ float sa[32], sb[32];
    int r0 = blockIdx.x * 32;
    if (t < 32) {
      int r = r0 + t;
      if (r < DM1) {
        slo[t] = g_rlo[r]; smid[t] = g_rmid[r]; shi[t] = g_rhi[r];
        sa[t] = g_ra[r];   sb[t] = g_rb[r];
      }
    }
    __syncthreads();
    int b = t & 127, g = t >> 7;      // 4 groups x 8 rows
#pragma unroll
    for (int q = 0; q < 8; q++) {
      int rr = g * 8 + q;
      int r = r0 + rr;
      if (r >= DM1) break;
      float sl = g_S[(size_t)slo[rr]  * NB + b];
      float sm = g_S[(size_t)smid[rr] * NB + b];
      float sh = g_S[(size_t)shi[rr]  * NB + b];
      g_hxT[(size_t)r * NB + b] = sa[rr] * (sm - sl) + sb[rr] * (sh - sm);
    }
    return;
  }
  // ---- logits (2-col hoist, NOTE16) ----
  __shared__ int   sr[32][CMAX];
  __shared__ float sv[32][CMAX];
  __shared__ float s1s[4][128], s2s[4][128];
  int c0 = ((int)blockIdx.x - SCB) * 32;
  {
    int cc = t >> 4, l = t & 15;   // 512 threads = 32x16 exactly
    sr[cc][l] = g_crow[(size_t)(c0 + cc) * CMAX + l];
    sv[cc][l] = g_cval[(size_t)(c0 + cc) * CMAX + l];
  }
  __syncthreads();
  int b = t & 127;
  int qg = t >> 7;                 // 0..3
  float s1 = 0.f, s2 = 0.f;
#pragma unroll
  for (int q = 0; q < 8; q += 2) {
    int cc = qg * 8 + q;
    unsigned short ev[2][CMAX];    // 32 independent gathers in flight
#pragma unroll
    for (int j = 0; j < 2; j++)
#pragma unroll
      for (int l = 0; l < CMAX; l++)
        ev[j][l] = g_etaTb[(size_t)sr[cc + j][l] * NB + b];
    float lxv[2];
#pragma unroll
    for (int j = 0; j < 2; j++)
      lxv[j] = g_lxT[(size_t)(c0 + cc + j) * NB + b];
#pragma unroll
    for (int j = 0; j < 2; j++) {
      float lg = 0.f;
#pragma unroll
      for (int l = 0; l < CMAX; l++)
        lg += sv[cc + j][l] * __uint_as_float((unsigned)ev[j][l] << 16);
      s1 += expf(lg);
      s2 += (expf(lxv[j]) - 1.0f) * lg;
    }
  }
  s1s[qg][b] = s1;
  s2s[qg][b] = s2;
  __syncthreads();
  if (qg == 0) {
    atomicAdd(&g_S1[b], s1s[0][b] + s1s[1][b] + s1s[2][b] + s1s[3][b]);
    atomicAdd(&g_S2[b], s2s[0][b] + s2s[1][b] + s2s[2][b] + s2s[3][b]);
  }
}

// ---- fused triple GEMM via bf16 hi/lo-split MFMA ---------------------------
// grid (KS, 6): y = mat*2 + jhalf. Block: C tile 128i x 64j, 512 threads =
// 8 waves of one 32x32 MFMA tile each. BK=32 staged per round (b128-only LDS
// at 80B stride -> 0 bank conflicts; NOTE7). Non-pipelined (NOTE12).
// mat 0: A=dec, B=dec -> WtW   mat 1: A=etaTb (bf16; lo==0, a_l MFMA
// skipped -- NOTE17), B=dec -> e0   mat 2: A=g_hxT, B=enc -> z
__global__ __launch_bounds__(512)
void k_atb3(const void* __restrict__ dec, const void* __restrict__ enc) {
  __shared__ unsigned short Ah[128][40], Al[128][40];
  __shared__ unsigned short Bh[64][40],  Bl[64][40];
  int f32 = g_f32flag;
  int mat = blockIdx.y >> 1;
  int j0 = (blockIdx.y & 1) * 64;
  int ks = blockIdx.x * GCH;
  int ke = min(ks + GCH, DM1);
  int t = threadIdx.x;
  int lane = t & 63;
  int w = t >> 6;            // wave 0..7
  int wi = (w >> 1) * 32;    // row tile base
  int wj = (w & 1) * 32;     // col tile base (within 64)
  int ai = t & 127;          // A stage: column i
  int akg = t >> 7;          // A stage: k-group (0..3), 8 k each
  int bj = t & 63;           // B stage: column j (threads 0..255)
  int bkg = (t >> 6) & 3;    // B stage: k-group

  f32x16 acc;
#pragma unroll
  for (int r = 0; r < 16; r++) acc[r] = 0.f;

  for (int kb = ks; kb < ke; kb += 32) {
    float av[8];
#pragma unroll
    for (int q = 0; q < 8; q++) {
      int k = kb + akg * 8 + q;
      float v = 0.f;
      if (k < ke) {
        if (mat == 2)      v = g_hxT[(size_t)k * NB + ai];
        else if (mat == 1) v = __uint_as_float(
                                 (unsigned)g_etaTb[(size_t)k * NB + ai] << 16);
        else               v = load_in(dec, (size_t)k * 128 + ai, f32);
      }
      av[q] = v;
    }
    float bv[8];
    if (t < 256) {
#pragma unroll
      for (int q = 0; q < 8; q++) {
        int k = kb + bkg * 8 + q;
        float v = 0.f;
        if (k < ke) {
          if (mat == 2) v = load_in(enc, (size_t)(j0 + bj) * DM1 + k, f32);
          else          v = load_in(dec, (size_t)k * 128 + j0 + bj, f32);
        }
        bv[q] = v;
      }
    }
    __syncthreads();   // previous round's fragment reads complete
    {
      short8v h8, l8;
#pragma unroll
      for (int q = 0; q < 8; q++) {
        unsigned short h = f2bf(av[q]);
        float hf = __uint_as_float((unsigned)h << 16);
        h8[q] = (short)h;
        l8[q] = (short)f2bf(av[q] - hf);
      }
      *(short8v*)&Ah[ai][akg * 8] = h8;
      *(short8v*)&Al[ai][akg * 8] = l8;
    }
    if (t < 256) {
      short8v h8, l8;
#pragma unroll
      for (int q = 0; q < 8; q++) {
        unsigned short h = f2bf(bv[q]);
        float hf = __uint_as_float((unsigned)h << 16);
        h8[q] = (short)h;
        l8[q] = (short)f2bf(bv[q] - hf);
      }
      *(short8v*)&Bh[bj][bkg * 8] = h8;
      *(short8v*)&Bl[bj][bkg * 8] = l8;
    }
    __syncthreads();   // tile ready
#pragma unroll
    for (int s = 0; s < 2; s++) {
      int k0 = s * 16 + (lane >> 5) * 8;
      int ar = wi + (lane & 31);
      int bc = wj + (lane & 31);
      short8v a_h = *(const short8v*)&Ah[ar][k0];
      short8v b_h = *(const short8v*)&Bh[bc][k0];
      short8v b_l = *(const short8v*)&Bl[bc][k0];
      acc = __builtin_amdgcn_mfma_f32_32x32x16_bf16(a_h, b_h, acc, 0, 0, 0);
      if (mat != 1) {   // A-lo is identically 0 for mat 1 (NOTE17)
        short8v a_l = *(const short8v*)&Al[ar][k0];
        acc = __builtin_amdgcn_mfma_f32_32x32x16_bf16(a_l, b_h, acc, 0, 0, 0);
      }
      acc = __builtin_amdgcn_mfma_f32_32x32x16_bf16(a_h, b_l, acc, 0, 0, 0);
    }
  }
  // C/D layout: col=lane&31, row=(r&3)+8*(r>>2)+4*(lane>>5)
  float* dst = g_pc + (size_t)blockIdx.x * 49152 + mat * 16384;
  int col = j0 + wj + (lane & 31);
#pragma unroll
  for (int r = 0; r < 16; r++) {
    int row = wi + (r & 3) + 8 * (r >> 2) + 4 * (lane >> 5);
    dst[row * 128 + col] = acc[r];
  }
}

// full reduction of KS partials; PLAIN stores (one writer per element).
// 768 blocks (round-8 exact), 4 threads per element + LDS combine.
__global__ __launch_bounds__(256)
void k_red3() {
  __shared__ float sh[256];
  int t = threadIdx.x;
  int e = blockIdx.x * 64 + (t & 63);
  int sg = t >> 6;               // 0..3
  float acc = 0.f;
#pragma unroll 8
  for (int s = sg * 32; s < sg * 32 + 32; s++)
    acc += g_pc[(size_t)s * 49152 + e];
  sh[t] = acc;
  __syncthreads();
  if (t < 64) {
    float v = sh[t] + sh[t + 64] + sh[t + 128] + sh[t + 192];
    int g = blockIdx.x * 64 + t;
    int m = g >> 14, e2 = g & 16383;
    if (m == 0) g_WtW[e2] = v;
    else if (m == 1) g_e0[e2] = v;
    else g_zT[(e2 & 127) * 128 + (e2 >> 7)] = v;   // zT[h][b]
  }
}

// ---- merged p2t (traces of P) + upost (Neumann quad terms) -----------------
__global__ __launch_bounds__(128)
void k_pu(const void* __restrict__ logvars, const void* __restrict__ lsq) {
  __shared__ float sh0[128], sh1[128], sh2[128], sh3[128], sh4[128], sh5[128];
  __shared__ float sds[128];
  int j = threadIdx.x;
  int f32 = g_f32flag;
  float invvar = expf(-load_in(lsq, 0, f32));
  sds[j] = expf(0.5f * load_in(logvars, j, f32));
  __syncthreads();
  if ((int)blockIdx.x < 128) {
    int i = blockIdx.x;
    float sdj = sds[j];
    float p = sds[i] * sdj * g_WtW[i * 128 + j] * invvar;
    sh0[j] = p;
    __syncthreads();
    float acc = 0.f;
    for (int k = 0; k < 128; k++)
      acc += sh0[k] * (sds[k] * sdj * g_WtW[k * 128 + j] * invvar);
    float v1 = wave_red_sum((i == j) ? p : 0.f);
    float v2 = wave_red_sum(p * p);
    float v3 = wave_red_sum(p * acc);
    float v4 = wave_red_sum(acc * acc);
    if ((j & 63) == 0) {
      atomicAdd(&g_tr[0], v1);
      atomicAdd(&g_tr[1], v2);
      atomicAdd(&g_tr[2], v3);
      atomicAdd(&g_tr[3], v4);
    }
  } else {
    int b = blockIdx.x - 128, k = j;
    float sdk = sds[k];
    sh0[k] = g_zT[(size_t)k * 128 + b];   // z[b, k]
    __syncthreads();
    float e0k = g_e0[b * 128 + k];
    float zWk = 0.f;
    for (int m = 0; m < 128; m++) zWk += sh0[m] * g_WtW[m * 128 + k];
    float u = (e0k - zWk) * sdk;
    sh1[k] = u;
    sh5[k] = sh0[k] * (zWk - 2.f * e0k);
    __syncthreads();
    float v1 = 0.f;
    for (int m = 0; m < 128; m++) v1 += sds[m] * g_WtW[m * 128 + k] * sh1[m];
    v1 *= sdk * invvar;
    sh2[k] = v1;
    __syncthreads();
    float v2 = 0.f;
    for (int m = 0; m < 128; m++) v2 += sds[m] * g_WtW[m * 128 + k] * sh2[m];
    v2 *= sdk * invvar;
    sh3[k] = v2;
    __syncthreads();
    float v3 = 0.f;
    for (int m = 0; m < 128; m++) v3 += sds[m] * g_WtW[m * 128 + k] * sh3[m];
    v3 *= sdk * invvar;
    sh4[k] = u * (u - v1 + v2 - v3);
    __syncthreads();
    for (int s = 64; s > 0; s >>= 1) {
      if (k < s) { sh4[k] += sh4[k + s]; sh5[k] += sh5[k + s]; }
      __syncthreads();
    }
    if (k == 0) {
      g_q2[b] = sh4[0];
      g_quad1[b] += sh5[0];   // quad1 held sum(eta^2) from scanB
    }
  }
}

// Output dtype: FLOAT32.
__global__ __launch_bounds__(128)
void k_final(const void* __restrict__ lsq, float* __restrict__ out) {
  __shared__ double red[128];
  __shared__ float redz[128];
  int b = threadIdx.x;
  int f32 = g_f32flag;
  float zs = 0.f;
  for (int i = b; i < 16384; i += 128) { float v = g_zT[i]; zs += v * v; }
  redz[b] = zs;
  const double LOG2PI = 1.837877066409345483560659472811;
  float lsqv = load_in(lsq, 0, f32);
  double var = exp((double)lsqv);
  double lse = log((double)g_S1[b]);
  double sumx = (double)g_sumx[b];
  double t1 = lgamma(sumx + 1.0) - (double)g_slg[b];
  double mult_b = t1 + (double)g_S2[b] - sumx * lse;
  double logdetM = (double)g_tr[0] - 0.5 * (double)g_tr[1]
                 + (1.0 / 3.0) * (double)g_tr[2] - 0.25 * (double)g_tr[3];
  double logdet = (double)DM1 * (double)lsqv + logdetM;
  double quad_b = (double)g_quad1[b] / var - (double)g_q2[b] / (var * var);
  double logit_b = -0.5 * ((double)DM1 * LOG2PI + logdet + quad_b);
  red[b] = mult_b + logit_b;
  __syncthreads();
  for (int s = 64; s > 0; s >>= 1) {
    if (b < s) { red[b] += red[b + s]; redz[b] += redz[b + s]; }
    __syncthreads();
  }
  if (b == 0) {
    double ml = red[0] / 128.0;  // mean_b(mult + logit)
    double prior = -0.5 * (double)redz[0] / 16384.0 - 0.5 * LOG2PI;
    out[0] = (float)(-(ml + prior));
  }
}

extern "C" void kernel_launch(void* const* d_in, const int* in_sizes, int n_in,
                              void* d_out, int out_size, void* d_ws, size_t ws_size,
                              hipStream_t stream) {
  const void* x     = d_in[0];
  const int*  rows  = (const int*)d_in[1];
  const int*  cols  = (const int*)d_in[2];
  const void* vals  = d_in[3];
  const void* enc_w = d_in[4];
  const void* dec_w = d_in[5];
  const void* lvars = d_in[6];
  const void* lsq   = d_in[7];
  const void* eta   = d_in[8];
  float* out = (float*)d_out;
  int nnz = in_sizes[1];
  (void)d_ws; (void)ws_size;

  int nbc = (nnz + 255) / 256;
  int nbr = (DM1 + 255) / 256;

  k_trans2<<<dim3(2 * SCB, 4), dim3(32, 8), 0, stream>>>(x, eta);  // + zero/probe
  k_aux<<<nbc + nbr + 128, 256, 0, stream>>>(rows, cols, vals, nnz, nbc, nbr);
  k_scanC_S<<<SCB, 512, 0, stream>>>();                 // S prefix (depth 8)
  k_hxlg<<<2 * SCB, 512, 0, stream>>>();                // hx | logits fused
  k_atb3<<<dim3(KS, 6), 512, 0, stream>>>(dec_w, enc_w);// WtW|e0|z partials (MFMA)
  k_red3<<<768, 256, 0, stream>>>();
  k_pu<<<256, 128, 0, stream>>>(lvars, lsq);            // traces + quad terms
  k_final<<<1, 128, 0, stream>>>(lsq, out);
}